// Round 4
// baseline (2441.975 us; speedup 1.0000x reference)
//
#include <hip/hip_runtime.h>
#include <math.h>

#define NNODES 5000
#define NEDGES 50000
#define NELG   200000
#define DMODEL 512
#define NH     8
#define NLAYERS 2

typedef __bf16 bf16x8 __attribute__((ext_vector_type(8)));
typedef float  f32x4  __attribute__((ext_vector_type(4)));
typedef unsigned short us8v __attribute__((ext_vector_type(8)));
typedef unsigned short us4v __attribute__((ext_vector_type(4)));

// ---- bf16 helpers (stored as unsigned short) ------------------------------
__device__ __forceinline__ float b2f(unsigned short u) {
    union { unsigned int i; float f; } c;
    c.i = ((unsigned int)u) << 16;
    return c.f;
}
__device__ __forceinline__ unsigned short f2b(float f) {
    union { float f; unsigned int i; } c;
    c.f = f;
    unsigned int i = c.i;
    return (unsigned short)((i + 0x7fffu + ((i >> 16) & 1u)) >> 16);
}

struct GemmDst {
    unsigned short* C0; unsigned short* C1; unsigned short* C2;
    const unsigned short* a0; const unsigned short* a1; const unsigned short* a2;
    const int* x0; const int* x1; const int* x2;
    const float* b0; const float* b1; const float* b2;
};

// ---------------------------------------------------------------------------
// 128^2 GEMM (round-3, proven): BK=32, 16 KB LDS, __syncthreads, XCD panel
// swizzle, swapped-operand MFMA -> vectorized D^T epilogue. Used for the
// node-scale GEMMs (M=5000) where grids are small and TLP covers latency.
// ---------------------------------------------------------------------------
#define BM 128
#define BN 128
#define BK 32

__global__ __launch_bounds__(256) void mfma_gemm_kernel(
    const unsigned short* __restrict__ A, const unsigned short* __restrict__ Bt,
    GemmDst P, int M, int K, int N, int secN, int relu)
{
    __shared__ __align__(16) unsigned short ldsA[BM * BK];  // 8 KB
    __shared__ __align__(16) unsigned short ldsB[BN * BK];  // 8 KB

    // ---- panel-to-XCD swizzle (bijective remap, dispatch wgid%8 = XCD) ----
    const int nbx  = gridDim.x;
    const int nb   = nbx * gridDim.y;
    const int wgid = blockIdx.y * nbx + blockIdx.x;
    const int xcd  = wgid & 7;
    const int ii   = wgid >> 3;
    const int q8   = nb >> 3, r8 = nb & 7;
    const int base = (xcd < r8) ? xcd * (q8 + 1) : r8 * (q8 + 1) + (xcd - r8) * q8;
    const int tl   = base + ii;
    const int rowBase = (tl / nbx) * BM;
    const int colBase = (tl % nbx) * BN;

    const int tid  = threadIdx.x;
    const int lane = tid & 63;
    const int wave = tid >> 6;
    const int quad = lane >> 4;
    const int l16  = lane & 15;
    const int wm = (wave >> 1) * 64;
    const int wn = (wave & 1) * 64;

    const int g0 = tid, g1 = tid + 256;
    const int r0 = g0 >> 2, r1 = g1 >> 2;
    const int c0g = (g0 & 3) ^ ((r0 >> 1) & 3);
    const int c1g = (g1 & 3) ^ ((r1 >> 1) & 3);
    int ra0 = rowBase + r0; if (ra0 > M - 1) ra0 = M - 1;
    int ra1 = rowBase + r1; if (ra1 > M - 1) ra1 = M - 1;
    const unsigned short* gA0 = A + (size_t)ra0 * K + c0g * 8;
    const unsigned short* gA1 = A + (size_t)ra1 * K + c1g * 8;
    const unsigned short* gB0 = Bt + (size_t)(colBase + r0) * K + c0g * 8;
    const unsigned short* gB1 = Bt + (size_t)(colBase + r1) * K + c1g * 8;
    unsigned short* lA0 = ldsA + g0 * 8;
    unsigned short* lA1 = ldsA + g1 * 8;
    unsigned short* lB0 = ldsB + g0 * 8;
    unsigned short* lB1 = ldsB + g1 * 8;

    const int swz = (l16 >> 1) & 3;
    const int ca = (quad ^ swz) * 8;

    const f32x4 zv = {0.f, 0.f, 0.f, 0.f};
    f32x4 acc[4][4];
    #pragma unroll
    for (int i = 0; i < 4; ++i)
        #pragma unroll
        for (int j = 0; j < 4; ++j) acc[i][j] = zv;

    for (int k0 = 0; k0 < K; k0 += BK) {
        __builtin_amdgcn_global_load_lds(
            (const __attribute__((address_space(1))) void*)(gA0 + k0),
            (__attribute__((address_space(3))) void*)lA0, 16, 0, 0);
        __builtin_amdgcn_global_load_lds(
            (const __attribute__((address_space(1))) void*)(gA1 + k0),
            (__attribute__((address_space(3))) void*)lA1, 16, 0, 0);
        __builtin_amdgcn_global_load_lds(
            (const __attribute__((address_space(1))) void*)(gB0 + k0),
            (__attribute__((address_space(3))) void*)lB0, 16, 0, 0);
        __builtin_amdgcn_global_load_lds(
            (const __attribute__((address_space(1))) void*)(gB1 + k0),
            (__attribute__((address_space(3))) void*)lB1, 16, 0, 0);
        __syncthreads();

        bf16x8 af[4], bfr[4];
        #pragma unroll
        for (int i = 0; i < 4; ++i)
            af[i] = *(const bf16x8*)(ldsA + (wm + i * 16 + l16) * BK + ca);
        #pragma unroll
        for (int j = 0; j < 4; ++j)
            bfr[j] = *(const bf16x8*)(ldsB + (wn + j * 16 + l16) * BK + ca);
        #pragma unroll
        for (int i = 0; i < 4; ++i)
            #pragma unroll
            for (int j = 0; j < 4; ++j)
                acc[i][j] = __builtin_amdgcn_mfma_f32_16x16x32_bf16(
                    bfr[j], af[i], acc[i][j], 0, 0, 0);
        __syncthreads();
    }

    const int sec   = colBase / secN;
    const int cbase = colBase - sec * secN;
    unsigned short*       Cs = (sec == 0) ? P.C0 : ((sec == 1) ? P.C1 : P.C2);
    const unsigned short* ad = (sec == 0) ? P.a0 : ((sec == 1) ? P.a1 : P.a2);
    const int*            gx = (sec == 0) ? P.x0 : ((sec == 1) ? P.x1 : P.x2);
    const float*          bs = (sec == 0) ? P.b0 : ((sec == 1) ? P.b1 : P.b2);

    f32x4 b4[4];
    #pragma unroll
    for (int j = 0; j < 4; ++j) {
        const int n0 = cbase + wn + j * 16 + quad * 4;
        b4[j] = bs ? *(const f32x4*)(bs + n0) : zv;
    }

    #pragma unroll
    for (int i = 0; i < 4; ++i) {
        const int row = rowBase + wm + i * 16 + l16;
        if (row >= M) continue;
        const int arow = gx ? gx[row] : row;
        const unsigned short* ar = ad ? ad + (size_t)arow * secN : nullptr;
        unsigned short* crow = Cs + (size_t)row * secN;
        #pragma unroll
        for (int j = 0; j < 4; ++j) {
            const int n0 = cbase + wn + j * 16 + quad * 4;
            f32x4 v = acc[i][j];
            v += b4[j];
            if (ar) {
                const us4v r4 = *(const us4v*)(ar + n0);
                #pragma unroll
                for (int r = 0; r < 4; ++r) v[r] += b2f(r4[r]);
            }
            if (relu) {
                #pragma unroll
                for (int r = 0; r < 4; ++r) v[r] = fmaxf(v[r], 0.0f);
            }
            us4v o4;
            #pragma unroll
            for (int r = 0; r < 4; ++r) o4[r] = f2b(v[r]);
            *(us4v*)(crow + n0) = o4;
        }
    }
}

// ---------------------------------------------------------------------------
// 256^2 GEMM, counted-vmcnt 2-deep pipeline (T3/T4 regime: per-K-tile 64
// MFMA/wave covers L2-hit staging latency; loads stay in flight ACROSS raw
// s_barriers). BK=64, 8 waves (2M x 4N), LDS 128 KB dbuf. Same XOR swizzle
// (mod 8) via pre-swizzled global source; same D^T vectorized epilogue.
// Used for the edge-scale GEMMs (M >= 12500).
// ---------------------------------------------------------------------------
#define TM 256
#define TN 256
#define TK 64

__global__ __launch_bounds__(512, 2) void mfma_gemm256_kernel(
    const unsigned short* __restrict__ A, const unsigned short* __restrict__ Bt,
    GemmDst P, int M, int K, int N, int secN, int relu)
{
    __shared__ __align__(16) unsigned short ldsA[2][TM * TK];  // 2 x 32 KB
    __shared__ __align__(16) unsigned short ldsB[2][TN * TK];  // 2 x 32 KB

    // ---- panel-to-XCD swizzle ----
    const int nbx  = gridDim.x;
    const int nb   = nbx * gridDim.y;
    const int wgid = blockIdx.y * nbx + blockIdx.x;
    const int xcd  = wgid & 7;
    const int ii   = wgid >> 3;
    const int q8   = nb >> 3, r8 = nb & 7;
    const int base = (xcd < r8) ? xcd * (q8 + 1) : r8 * (q8 + 1) + (xcd - r8) * q8;
    const int tl   = base + ii;
    const int rowBase = (tl / nbx) * TM;
    const int colBase = (tl % nbx) * TN;

    const int tid  = threadIdx.x;           // 0..511
    const int lane = tid & 63;
    const int wave = tid >> 6;               // 0..7
    const int quad = lane >> 4;
    const int l16  = lane & 15;
    const int wr   = wave >> 2;              // 0..1 (M)
    const int wc   = wave & 3;               // 0..3 (N)

    // staging map: linear chunk p = j*512+tid (16 B), row r=p>>3, slot s=p&7,
    // slot holds global chunk c = s ^ (r&7) (involution, pre-swizzled source)
    const unsigned short* srcA[4];
    const unsigned short* srcB[4];
    int ldsOff[4];
    #pragma unroll
    for (int j = 0; j < 4; ++j) {
        const int p = j * 512 + tid;
        const int r = p >> 3;
        const int c = (p & 7) ^ (r & 7);
        ldsOff[j] = p * 8;
        int rA = rowBase + r; if (rA > M - 1) rA = M - 1;
        srcA[j] = A + (size_t)rA * K + c * 8;
        srcB[j] = Bt + (size_t)(colBase + r) * K + c * 8;
    }

    // read-side: global chunk q = ks*4+quad of row (..+l16) is at slot q^(l16&7)
    const int ca0 = (quad       ^ (l16 & 7)) * 8;
    const int ca1 = ((quad + 4) ^ (l16 & 7)) * 8;
    const int aRow0 = wr * 128 + l16;
    const int bRow0 = wc * 64 + l16;

    const f32x4 zv = {0.f, 0.f, 0.f, 0.f};
    f32x4 acc[8][4];
    #pragma unroll
    for (int i = 0; i < 8; ++i)
        #pragma unroll
        for (int j = 0; j < 4; ++j) acc[i][j] = zv;

#define STAGE256(buf, t)                                                      \
    {                                                                         \
        unsigned short* dA = ldsA[buf];                                       \
        unsigned short* dB = ldsB[buf];                                       \
        const int ko = (t) * TK;                                              \
        _Pragma("unroll")                                                     \
        for (int j = 0; j < 4; ++j)                                           \
            __builtin_amdgcn_global_load_lds(                                 \
                (const __attribute__((address_space(1))) void*)(srcA[j] + ko),\
                (__attribute__((address_space(3))) void*)(dA + ldsOff[j]),    \
                16, 0, 0);                                                    \
        _Pragma("unroll")                                                     \
        for (int j = 0; j < 4; ++j)                                           \
            __builtin_amdgcn_global_load_lds(                                 \
                (const __attribute__((address_space(1))) void*)(srcB[j] + ko),\
                (__attribute__((address_space(3))) void*)(dB + ldsOff[j]),    \
                16, 0, 0);                                                    \
    }

#define COMPUTE256(buf)                                                       \
    {                                                                         \
        const unsigned short* bA = ldsA[buf];                                 \
        const unsigned short* bB = ldsB[buf];                                 \
        _Pragma("unroll")                                                     \
        for (int ks = 0; ks < 2; ++ks) {                                      \
            const int cs = ks ? ca1 : ca0;                                    \
            bf16x8 afr[8], bfr[4];                                            \
            _Pragma("unroll")                                                 \
            for (int m = 0; m < 8; ++m)                                       \
                afr[m] = *(const bf16x8*)(bA + (aRow0 + m * 16) * TK + cs);   \
            _Pragma("unroll")                                                 \
            for (int n = 0; n < 4; ++n)                                       \
                bfr[n] = *(const bf16x8*)(bB + (bRow0 + n * 16) * TK + cs);   \
            _Pragma("unroll")                                                 \
            for (int m = 0; m < 8; ++m)                                       \
                _Pragma("unroll")                                             \
                for (int n = 0; n < 4; ++n)                                   \
                    acc[m][n] = __builtin_amdgcn_mfma_f32_16x16x32_bf16(      \
                        bfr[n], afr[m], acc[m][n], 0, 0, 0);                  \
        }                                                                     \
    }

    const int nt = K / TK;     // >= 2 at all call sites (K >= 512)

    // prologue: tiles 0,1 in flight (16 outstanding); wait tile 0 (own 8)
    STAGE256(0, 0);
    STAGE256(1, 1);
    asm volatile("s_waitcnt vmcnt(8)" ::: "memory");
    __builtin_amdgcn_s_barrier();
    __builtin_amdgcn_sched_barrier(0);

    for (int t = 0; t < nt - 2; ++t) {
        COMPUTE256(t & 1);
        __builtin_amdgcn_sched_barrier(0);
        __builtin_amdgcn_s_barrier();        // all waves done reading buf t&1
        STAGE256(t & 1, t + 2);              // overwrite; 16 outstanding
        asm volatile("s_waitcnt vmcnt(8)" ::: "memory");  // own t+1 landed
        __builtin_amdgcn_s_barrier();        // => all waves' t+1 landed
        __builtin_amdgcn_sched_barrier(0);
    }
    COMPUTE256(nt & 1);                      // tile nt-2 lives in buf (nt-2)&1
    __builtin_amdgcn_sched_barrier(0);
    asm volatile("s_waitcnt vmcnt(0)" ::: "memory");
    __builtin_amdgcn_s_barrier();
    __builtin_amdgcn_sched_barrier(0);
    COMPUTE256((nt - 1) & 1);

#undef STAGE256
#undef COMPUTE256

    const int sec   = colBase / secN;
    const int cbase = colBase - sec * secN;
    unsigned short*       Cs = (sec == 0) ? P.C0 : ((sec == 1) ? P.C1 : P.C2);
    const unsigned short* ad = (sec == 0) ? P.a0 : ((sec == 1) ? P.a1 : P.a2);
    const int*            gx = (sec == 0) ? P.x0 : ((sec == 1) ? P.x1 : P.x2);
    const float*          bs = (sec == 0) ? P.b0 : ((sec == 1) ? P.b1 : P.b2);

    f32x4 b4[4];
    #pragma unroll
    for (int n = 0; n < 4; ++n) {
        const int n0 = cbase + wc * 64 + n * 16 + quad * 4;
        b4[n] = bs ? *(const f32x4*)(bs + n0) : zv;
    }

    #pragma unroll
    for (int m = 0; m < 8; ++m) {
        const int row = rowBase + wr * 128 + m * 16 + l16;
        if (row >= M) continue;
        const int arow = gx ? gx[row] : row;
        const unsigned short* ar = ad ? ad + (size_t)arow * secN : nullptr;
        unsigned short* crow = Cs + (size_t)row * secN;
        #pragma unroll
        for (int n = 0; n < 4; ++n) {
            const int n0 = cbase + wc * 64 + n * 16 + quad * 4;
            f32x4 v = acc[m][n];
            v += b4[n];
            if (ar) {
                const us4v r4 = *(const us4v*)(ar + n0);
                #pragma unroll
                for (int r = 0; r < 4; ++r) v[r] += b2f(r4[r]);
            }
            if (relu) {
                #pragma unroll
                for (int r = 0; r < 4; ++r) v[r] = fmaxf(v[r], 0.0f);
            }
            us4v o4;
            #pragma unroll
            for (int r = 0; r < 4; ++r) o4[r] = f2b(v[r]);
            *(us4v*)(crow + n0) = o4;
        }
    }
}

// ---------------------------------------------------------------------------
// W[K][N] fp32 -> Wt[N][K] bf16
// ---------------------------------------------------------------------------
__global__ __launch_bounds__(256) void transpose_cast_kernel(
    const float* __restrict__ W, unsigned short* __restrict__ Wt, int K, int N)
{
    __shared__ float t[32][33];
    const int n0 = blockIdx.x << 5, k0 = blockIdx.y << 5;
    const int tx = threadIdx.x & 31, ty = threadIdx.x >> 5;
    #pragma unroll
    for (int r = 0; r < 32; r += 8)
        t[ty + r][tx] = W[(size_t)(k0 + ty + r) * N + n0 + tx];
    __syncthreads();
    #pragma unroll
    for (int r = 0; r < 32; r += 8)
        Wt[(size_t)(n0 + ty + r) * K + k0 + tx] = f2b(t[tx][ty + r]);
}

// ---------------------------------------------------------------------------
// LayerNorm in place over bf16 rows of width 512. One wave per row.
// ---------------------------------------------------------------------------
__global__ __launch_bounds__(256) void ln_kernel(
    unsigned short* __restrict__ x, const float* __restrict__ g,
    const float* __restrict__ b, int M)
{
    const int row = blockIdx.x * 4 + (threadIdx.x >> 6);
    if (row >= M) return;
    const int lane = threadIdx.x & 63;
    unsigned short* xr = x + (size_t)row * DMODEL;

    float vals[8];
    float s = 0.f, s2 = 0.f;
    #pragma unroll
    for (int i = 0; i < 8; ++i) {
        const float v = b2f(xr[lane + i * 64]);
        vals[i] = v; s += v; s2 += v * v;
    }
    #pragma unroll
    for (int o = 32; o > 0; o >>= 1) {
        s  += __shfl_down(s, o);
        s2 += __shfl_down(s2, o);
    }
    s  = __shfl(s, 0);
    s2 = __shfl(s2, 0);
    const float m = s * (1.0f / DMODEL);
    const float var = s2 * (1.0f / DMODEL) - m * m;
    const float r = rsqrtf(var + 1e-5f);
    #pragma unroll
    for (int i = 0; i < 8; ++i) {
        const int c = lane + i * 64;
        xr[c] = f2b((vals[i] - m) * r * g[c] + b[c]);
    }
}

// ---------------------------------------------------------------------------
// CSR build: histogram -> single-block scan -> scatter
// ---------------------------------------------------------------------------
__global__ __launch_bounds__(256) void hist_kernel(
    const int* __restrict__ dst, int* __restrict__ cnt, int ne)
{
    const int j = blockIdx.x * 256 + threadIdx.x;
    if (j < ne) atomicAdd(&cnt[dst[j]], 1);
}

__global__ __launch_bounds__(1024) void scan_kernel(
    const int* __restrict__ cnt, int* __restrict__ off,
    int* __restrict__ cur, int n)
{
    __shared__ int part[1024];
    const int t = threadIdx.x;
    const int chunk = (n + 1023) >> 10;
    const int lo = t * chunk;
    int hi = lo + chunk; if (hi > n) hi = n;
    int s = 0;
    for (int i = lo; i < hi; ++i) s += cnt[i];
    part[t] = s;
    __syncthreads();
    #pragma unroll
    for (int o = 1; o < 1024; o <<= 1) {
        int v = (t >= o) ? part[t - o] : 0;
        __syncthreads();
        part[t] += v;
        __syncthreads();
    }
    int base = (t == 0) ? 0 : part[t - 1];
    const int total = part[1023];
    for (int i = lo; i < hi; ++i) {
        const int c = cnt[i];
        off[i] = base; cur[i] = base;
        base += c;
    }
    if (t == 1023) off[n] = total;
}

__global__ __launch_bounds__(256) void scatter_kernel(
    const int* __restrict__ dst, int* __restrict__ cur,
    int* __restrict__ idx, int ne)
{
    const int j = blockIdx.x * 256 + threadIdx.x;
    if (j < ne) {
        const int p = atomicAdd(&cur[dst[j]], 1);
        idx[p] = j;
    }
}

// ---------------------------------------------------------------------------
// Fused CSR attention: ONE WAVE per destination segment (4 segs/block).
// No LDS, no barriers, q row loaded once; lane covers 8 contiguous cols,
// head = 8 lanes, score reduced with 3 xor-shuffles.
// ---------------------------------------------------------------------------
__global__ __launch_bounds__(256) void attend_kernel(
    unsigned short* __restrict__ q,
    const unsigned short* __restrict__ k,
    const unsigned short* __restrict__ v,
    const unsigned short* __restrict__ efeat,
    const int* __restrict__ src,
    const int* __restrict__ off, const int* __restrict__ idx,
    int nseg)
{
    const int wave = threadIdx.x >> 6, lane = threadIdx.x & 63;
    const int seg = blockIdx.x * 4 + wave;
    if (seg >= nseg) return;
    const int c8 = lane * 8;
    unsigned short* qrow = q + (size_t)seg * DMODEL;

    const us8v q8 = *(const us8v*)(qrow + c8);
    float qv[8];
    #pragma unroll
    for (int j = 0; j < 8; ++j) qv[j] = b2f(q8[j]);

    float acc[8] = {0.f, 0.f, 0.f, 0.f, 0.f, 0.f, 0.f, 0.f};
    float zsum = 0.f;
    const int lo = off[seg], hi = off[seg + 1];
    for (int jj = lo; jj < hi; ++jj) {
        const int e = idx[jj];
        const int s = src[e];
        const us8v k8 = *(const us8v*)(k + (size_t)s * DMODEL + c8);
        const us8v v8 = *(const us8v*)(v + (size_t)s * DMODEL + c8);
        float p = 0.f;
        float vv[8];
        if (efeat) {
            const us8v e8 = *(const us8v*)(efeat + (size_t)e * DMODEL + c8);
            #pragma unroll
            for (int j = 0; j < 8; ++j) {
                const float ef = b2f(e8[j]);
                p = fmaf(b2f(k8[j]) + ef, qv[j], p);
                vv[j] = b2f(v8[j]) + ef;
            }
        } else {
            #pragma unroll
            for (int j = 0; j < 8; ++j) {
                p = fmaf(b2f(k8[j]), qv[j], p);
                vv[j] = b2f(v8[j]);
            }
        }
        p += __shfl_xor(p, 1);
        p += __shfl_xor(p, 2);
        p += __shfl_xor(p, 4);
        float sc = p * 0.125f;                    // 1/sqrt(64)
        sc = fminf(fmaxf(sc, -10.0f), 10.0f);
        sc = __expf(sc);
        zsum += sc;
        #pragma unroll
        for (int j = 0; j < 8; ++j) acc[j] = fmaf(sc, vv[j], acc[j]);
    }

    const float rz = 1.0f / zsum;
    us8v o8;
    #pragma unroll
    for (int j = 0; j < 8; ++j) o8[j] = f2b(acc[j] * rz);
    *(us8v*)(qrow + c8) = o8;
}

// ---------------------------------------------------------------------------
__global__ __launch_bounds__(256) void gather_rel_kernel(
    const float* __restrict__ rel, const int* __restrict__ ef,
    unsigned short* __restrict__ lg)
{
    const int idx = blockIdx.x * 256 + threadIdx.x;
    if (idx >= NEDGES * DMODEL) return;
    const int e = idx >> 9;
    const int col = idx & 511;
    lg[idx] = f2b(rel[(size_t)ef[e] * DMODEL + col]);
}

__global__ __launch_bounds__(256) void cast_f2b_kernel(
    const float* __restrict__ in, unsigned short* __restrict__ out, int n)
{
    const int idx = blockIdx.x * 256 + threadIdx.x;
    if (idx < n) out[idx] = f2b(in[idx]);
}

__global__ __launch_bounds__(256) void cast_b2f_kernel(
    const unsigned short* __restrict__ in, float* __restrict__ out, int n)
{
    const int idx = blockIdx.x * 256 + threadIdx.x;
    if (idx < n) out[idx] = b2f(in[idx]);
}

__global__ __launch_bounds__(256) void zero_kernel(float4* __restrict__ p, int n4)
{
    const int idx = blockIdx.x * 256 + threadIdx.x;
    if (idx < n4) p[idx] = make_float4(0.f, 0.f, 0.f, 0.f);
}

// ---------------------------------------------------------------------------
static inline void mgemm(hipStream_t st, const unsigned short* A, const unsigned short* Bt,
                         const float* bias, const unsigned short* add, const int* gidx,
                         unsigned short* C, int M, int K, int N, int relu)
{
    GemmDst P = {C, nullptr, nullptr, add, nullptr, nullptr,
                 gidx, nullptr, nullptr, bias, nullptr, nullptr};
    dim3 g(N / BN, (M + BM - 1) / BM);
    mfma_gemm_kernel<<<g, 256, 0, st>>>(A, Bt, P, M, K, N, N, relu);
}

static inline void mgemm_qkv(hipStream_t st, const unsigned short* A, const unsigned short* Bt,
                             const float* biasQ,
                             const unsigned short* addQ, const int* gxQ,
                             const unsigned short* addKV, const int* gxKV,
                             unsigned short* Cq, unsigned short* Ck, unsigned short* Cv,
                             int M, int K)
{
    GemmDst P = {Cq, Ck, Cv, addQ, addKV, addKV,
                 gxQ, gxKV, gxKV, biasQ, nullptr, nullptr};
    dim3 g(1536 / BN, (M + BM - 1) / BM);
    mfma_gemm_kernel<<<g, 256, 0, st>>>(A, Bt, P, M, K, 1536, 512, 0);
}

static inline void mgemm256(hipStream_t st, const unsigned short* A, const unsigned short* Bt,
                            const float* bias, const unsigned short* add, const int* gidx,
                            unsigned short* C, int M, int K, int N, int relu)
{
    GemmDst P = {C, nullptr, nullptr, add, nullptr, nullptr,
                 gidx, nullptr, nullptr, bias, nullptr, nullptr};
    dim3 g(N / TN, (M + TM - 1) / TM);
    mfma_gemm256_kernel<<<g, 512, 0, st>>>(A, Bt, P, M, K, N, N, relu);
}

static inline void mgemm256_qkv(hipStream_t st, const unsigned short* A, const unsigned short* Bt,
                                const float* biasQ,
                                const unsigned short* addQ, const int* gxQ,
                                const unsigned short* addKV, const int* gxKV,
                                unsigned short* Cq, unsigned short* Ck, unsigned short* Cv,
                                int M, int K)
{
    GemmDst P = {Cq, Ck, Cv, addQ, addKV, addKV,
                 gxQ, gxKV, gxKV, biasQ, nullptr, nullptr};
    dim3 g(1536 / TN, (M + TM - 1) / TM);
    mfma_gemm256_kernel<<<g, 512, 0, st>>>(A, Bt, P, M, K, 1536, 512, 0);
}

static inline void tcast(hipStream_t st, const float* W, unsigned short* Wt, int K, int N)
{
    dim3 g(N / 32, K / 32);
    transpose_cast_kernel<<<g, 256, 0, st>>>(W, Wt, K, N);
}
static inline void zero(hipStream_t st, void* p, size_t nfloats)
{
    const int n4 = (int)(nfloats / 4);
    zero_kernel<<<(n4 + 255) / 256, 256, 0, st>>>((float4*)p, n4);
}

extern "C" void kernel_launch(void* const* d_in, const int* in_sizes, int n_in,
                              void* d_out, int out_size, void* d_ws, size_t ws_size,
                              hipStream_t stream)
{
    const float* x_in      = (const float*)d_in[0];
    const int*   edge_feat = (const int*)d_in[1];
    const int*   src_ids   = (const int*)d_in[2];
    const int*   dst_ids   = (const int*)d_in[3];
    const int*   lg_src    = (const int*)d_in[4];
    const int*   lg_dst    = (const int*)d_in[5];
    const float* rel_embed = (const float*)d_in[6];

    const float* n_Wq = (const float*)d_in[7];   const float* n_bq = (const float*)d_in[8];
    const float* n_Wk = (const float*)d_in[9];   const float* n_Wv = (const float*)d_in[10];
    const float* n_Wo = (const float*)d_in[11];  const float* n_bo = (const float*)d_in[12];
    const float* n_lg = (const float*)d_in[13];  const float* n_lb = (const float*)d_in[14];
    const float* n_f1 = (const float*)d_in[15];  const float* n_fb1 = (const float*)d_in[16];
    const float* n_f2 = (const float*)d_in[17];  const float* n_fb2 = (const float*)d_in[18];
    const float* n_fg = (const float*)d_in[19];  const float* n_fb = (const float*)d_in[20];

    const float* e_Wq = (const float*)d_in[21];  const float* e_bq = (const float*)d_in[22];
    const float* e_Wk = (const float*)d_in[23];  const float* e_Wv = (const float*)d_in[24];
    const float* e_Wo = (const float*)d_in[25];  const float* e_bo = (const float*)d_in[26];
    const float* e_lg = (const float*)d_in[27];  const float* e_lb = (const float*)d_in[28];
    const float* e_f1 = (const float*)d_in[29];  const float* e_fb1 = (const float*)d_in[30];
    const float* e_f2 = (const float*)d_in[31];  const float* e_fb2 = (const float*)d_in[32];
    const float* e_fg = (const float*)d_in[33];  const float* e_fb = (const float*)d_in[34];

    const int XSZ  = NNODES * DMODEL;
    const int LGSZ = NEDGES * DMODEL;

    // ---- workspace layout ---------------------------------------------------
    char* ws = (char*)d_ws;
    unsigned short* lg16  = (unsigned short*)(ws);               // 51,200,000 B
    unsigned short* ve16  = (unsigned short*)(ws + 51200000);    // 51,200,000 B
    int* n_off = (int*)(ws + 102400000);
    int* n_cur = (int*)(ws + 102420480);
    int* n_idx = (int*)(ws + 102440960);
    int* e_off = (int*)(ws + 102641664);
    int* e_cur = (int*)(ws + 102842368);
    int* e_idx = (int*)(ws + 103043072);                         // ends 103.84 MB
    unsigned short* xbufA = (unsigned short*)(ws + 110400000);   // 5,120,000 B
    unsigned short* xbufB = (unsigned short*)(ws + 115520000);   // 5,120,000 B

    // ---- d_out scratch (112.64 MB) -----------------------------------------
    char* ob = (char*)d_out;
    unsigned short* qe16 = (unsigned short*)(ob);                // 51.2 MB
    unsigned short* ke16 = (unsigned short*)(ob + 51200000);     // 51.2 MB
    unsigned short* nq16 = (unsigned short*)(ob);
    unsigned short* nk16 = (unsigned short*)(ob + 5120000);
    unsigned short* nv16 = (unsigned short*)(ob + 10240000);
    unsigned short* nhid = (unsigned short*)(ob);                // 20.48 MB
    unsigned short* wtq  = (unsigned short*)(ob + 102400000);    // q|k|v contiguous
    unsigned short* wtk  = (unsigned short*)(ob + 102924288);
    unsigned short* wtv  = (unsigned short*)(ob + 103448576);
    unsigned short* wto  = (unsigned short*)(ob + 103972864);
    unsigned short* wtf1 = (unsigned short*)(ob + 104497152);    // 2 MB
    unsigned short* wtf2 = (unsigned short*)(ob + 106594304);    // 2 MB (ends 108.7 MB)

    // ---- init + CSR build ---------------------------------------------------
    cast_f2b_kernel<<<(XSZ + 255) / 256, 256, 0, stream>>>(x_in, xbufA, XSZ);
    gather_rel_kernel<<<(LGSZ + 255) / 256, 256, 0, stream>>>(rel_embed, edge_feat, lg16);

    zero(stream, n_cur, NNODES);
    zero(stream, e_cur, NEDGES);
    hist_kernel<<<(NEDGES + 255) / 256, 256, 0, stream>>>(dst_ids, n_cur, NEDGES);
    hist_kernel<<<(NELG + 255) / 256, 256, 0, stream>>>(lg_dst, e_cur, NELG);
    scan_kernel<<<1, 1024, 0, stream>>>(n_cur, n_off, n_cur, NNODES);
    scan_kernel<<<1, 1024, 0, stream>>>(e_cur, e_off, e_cur, NEDGES);
    scatter_kernel<<<(NEDGES + 255) / 256, 256, 0, stream>>>(dst_ids, n_cur, n_idx, NEDGES);
    scatter_kernel<<<(NELG + 255) / 256, 256, 0, stream>>>(lg_dst, e_cur, e_idx, NELG);

    unsigned short* xc = xbufA;
    unsigned short* xn = xbufB;

    for (int i = 0; i < NLAYERS; ++i) {
        const size_t wo  = (size_t)i * DMODEL * DMODEL;
        const size_t bo_ = (size_t)i * DMODEL;
        const size_t f1o = (size_t)i * DMODEL * 4 * DMODEL;
        const size_t b1o = (size_t)i * 4 * DMODEL;
        const size_t f2o = (size_t)i * 4 * DMODEL * DMODEL;

        // ================= node update (reads xc, lg16) =================
        tcast(stream, n_Wq + wo, wtq, 512, 512);
        tcast(stream, n_Wk + wo, wtk, 512, 512);
        tcast(stream, n_Wv + wo, wtv, 512, 512);
        tcast(stream, n_Wo + wo, wto, 512, 512);
        tcast(stream, n_f1 + f1o, wtf1, 512, 2048);
        tcast(stream, n_f2 + f2o, wtf2, 2048, 512);

        mgemm_qkv(stream, xc, wtq, n_bq + bo_,
                  nullptr, nullptr, nullptr, nullptr,
                  nq16, nk16, nv16, NNODES, 512);

        attend_kernel<<<(NNODES + 3) / 4, 256, 0, stream>>>(
            nq16, nk16, nv16, lg16, src_ids, n_off, n_idx, NNODES);

        mgemm(stream, nq16, wto, n_bo + bo_, xc, nullptr, xn, NNODES, 512, 512, 0);
        ln_kernel<<<(NNODES + 3) / 4, 256, 0, stream>>>(xn, n_lg + bo_, n_lb + bo_, NNODES);
        mgemm(stream, xn, wtf1, n_fb1 + b1o, nullptr, nullptr, nhid, NNODES, 512, 2048, 1);
        mgemm(stream, nhid, wtf2, n_fb2 + bo_, xn, nullptr, xn, NNODES, 2048, 512, 0);
        ln_kernel<<<(NNODES + 3) / 4, 256, 0, stream>>>(xn, n_fg + bo_, n_fb + bo_, NNODES);

        // ================= edge update (reads PRE-update xc) =================
        tcast(stream, e_Wq + wo, wtq, 512, 512);
        tcast(stream, e_Wk + wo, wtk, 512, 512);
        tcast(stream, e_Wv + wo, wtv, 512, 512);
        tcast(stream, e_Wo + wo, wto, 512, 512);

        mgemm256_qkv(stream, lg16, wtq, e_bq + bo_,
                     xc, dst_ids, xc, src_ids,
                     qe16, ke16, ve16, NEDGES, 512);

        attend_kernel<<<(NEDGES + 3) / 4, 256, 0, stream>>>(
            qe16, ke16, ve16, nullptr, lg_src, e_off, e_idx, NEDGES);

        mgemm256(stream, qe16, wto, e_bo + bo_, lg16, nullptr, lg16, NEDGES, 512, 512, 0);
        ln_kernel<<<(NEDGES + 3) / 4, 256, 0, stream>>>(lg16, e_lg + bo_, e_lb + bo_, NEDGES);

        tcast(stream, e_f1 + f1o, wtf1, 512, 2048);
        tcast(stream, e_f2 + f2o, wtf2, 2048, 512);
        for (int c = 0; c < 4; ++c) {
            unsigned short* y1c = lg16 + (size_t)c * 12500 * DMODEL;
            mgemm256(stream, y1c, wtf1, e_fb1 + b1o, nullptr, nullptr, ve16, 12500, 512, 2048, 1);
            mgemm256(stream, ve16, wtf2, e_fb2 + bo_, y1c, nullptr, y1c, 12500, 2048, 512, 0);
        }
        ln_kernel<<<(NEDGES + 3) / 4, 256, 0, stream>>>(lg16, e_fg + bo_, e_fb + bo_, NEDGES);

        unsigned short* t = xc; xc = xn; xn = t;
    }

    // final: bf16 -> fp32 d_out (all d_out scratch dead now)
    float* out_f = (float*)d_out;
    cast_b2f_kernel<<<(XSZ + 255) / 256, 256, 0, stream>>>(xc, out_f, XSZ);
    cast_b2f_kernel<<<(LGSZ + 255) / 256, 256, 0, stream>>>(lg16, out_f + XSZ, LGSZ);
}

// Round 6
// 2270.170 us; speedup vs baseline: 1.0757x; 1.0757x over previous
//
#include <hip/hip_runtime.h>
#include <math.h>

#define NNODES 5000
#define NEDGES 50000
#define NELG   200000
#define DMODEL 512
#define NH     8
#define NLAYERS 2

typedef __bf16 bf16x8 __attribute__((ext_vector_type(8)));
typedef float  f32x4  __attribute__((ext_vector_type(4)));
typedef unsigned short us8v __attribute__((ext_vector_type(8)));
typedef unsigned short us4v __attribute__((ext_vector_type(4)));

// ---- bf16 helpers (stored as unsigned short) ------------------------------
__device__ __forceinline__ float b2f(unsigned short u) {
    union { unsigned int i; float f; } c;
    c.i = ((unsigned int)u) << 16;
    return c.f;
}
__device__ __forceinline__ unsigned short f2b(float f) {
    union { float f; unsigned int i; } c;
    c.f = f;
    unsigned int i = c.i;
    return (unsigned short)((i + 0x7fffu + ((i >> 16) & 1u)) >> 16);
}

struct GemmDst {
    unsigned short* C0; unsigned short* C1; unsigned short* C2;
    const unsigned short* a0; const unsigned short* a1; const unsigned short* a2;
    const int* x0; const int* x1; const int* x2;
    const float* b0; const float* b1; const float* b2;
};

// ---------------------------------------------------------------------------
// 128^2 GEMM (round-3, proven): BK=32, 16 KB LDS, __syncthreads, XCD panel
// swizzle, swapped-operand MFMA -> vectorized D^T epilogue. 8 blocks/CU:
// used where grids are small/awkward (node GEMMs, N=512 GEMMs) — TLP covers
// latency and load balance beats the 1-block/CU 256^2 kernel.
// ---------------------------------------------------------------------------
#define BM 128
#define BN 128
#define BK 32

__global__ __launch_bounds__(256) void mfma_gemm_kernel(
    const unsigned short* __restrict__ A, const unsigned short* __restrict__ Bt,
    GemmDst P, int M, int K, int N, int secN, int relu)
{
    __shared__ __align__(16) unsigned short ldsA[BM * BK];  // 8 KB
    __shared__ __align__(16) unsigned short ldsB[BN * BK];  // 8 KB

    // ---- panel-to-XCD swizzle (bijective remap, dispatch wgid%8 = XCD) ----
    const int nbx  = gridDim.x;
    const int nb   = nbx * gridDim.y;
    const int wgid = blockIdx.y * nbx + blockIdx.x;
    const int xcd  = wgid & 7;
    const int ii   = wgid >> 3;
    const int q8   = nb >> 3, r8 = nb & 7;
    const int base = (xcd < r8) ? xcd * (q8 + 1) : r8 * (q8 + 1) + (xcd - r8) * q8;
    const int tl   = base + ii;
    const int rowBase = (tl / nbx) * BM;
    const int colBase = (tl % nbx) * BN;

    const int tid  = threadIdx.x;
    const int lane = tid & 63;
    const int wave = tid >> 6;
    const int quad = lane >> 4;
    const int l16  = lane & 15;
    const int wm = (wave >> 1) * 64;
    const int wn = (wave & 1) * 64;

    const int g0 = tid, g1 = tid + 256;
    const int r0 = g0 >> 2, r1 = g1 >> 2;
    const int c0g = (g0 & 3) ^ ((r0 >> 1) & 3);
    const int c1g = (g1 & 3) ^ ((r1 >> 1) & 3);
    int ra0 = rowBase + r0; if (ra0 > M - 1) ra0 = M - 1;
    int ra1 = rowBase + r1; if (ra1 > M - 1) ra1 = M - 1;
    const unsigned short* gA0 = A + (size_t)ra0 * K + c0g * 8;
    const unsigned short* gA1 = A + (size_t)ra1 * K + c1g * 8;
    const unsigned short* gB0 = Bt + (size_t)(colBase + r0) * K + c0g * 8;
    const unsigned short* gB1 = Bt + (size_t)(colBase + r1) * K + c1g * 8;
    unsigned short* lA0 = ldsA + g0 * 8;
    unsigned short* lA1 = ldsA + g1 * 8;
    unsigned short* lB0 = ldsB + g0 * 8;
    unsigned short* lB1 = ldsB + g1 * 8;

    const int swz = (l16 >> 1) & 3;
    const int ca = (quad ^ swz) * 8;

    const f32x4 zv = {0.f, 0.f, 0.f, 0.f};
    f32x4 acc[4][4];
    #pragma unroll
    for (int i = 0; i < 4; ++i)
        #pragma unroll
        for (int j = 0; j < 4; ++j) acc[i][j] = zv;

    for (int k0 = 0; k0 < K; k0 += BK) {
        __builtin_amdgcn_global_load_lds(
            (const __attribute__((address_space(1))) void*)(gA0 + k0),
            (__attribute__((address_space(3))) void*)lA0, 16, 0, 0);
        __builtin_amdgcn_global_load_lds(
            (const __attribute__((address_space(1))) void*)(gA1 + k0),
            (__attribute__((address_space(3))) void*)lA1, 16, 0, 0);
        __builtin_amdgcn_global_load_lds(
            (const __attribute__((address_space(1))) void*)(gB0 + k0),
            (__attribute__((address_space(3))) void*)lB0, 16, 0, 0);
        __builtin_amdgcn_global_load_lds(
            (const __attribute__((address_space(1))) void*)(gB1 + k0),
            (__attribute__((address_space(3))) void*)lB1, 16, 0, 0);
        __syncthreads();

        bf16x8 af[4], bfr[4];
        #pragma unroll
        for (int i = 0; i < 4; ++i)
            af[i] = *(const bf16x8*)(ldsA + (wm + i * 16 + l16) * BK + ca);
        #pragma unroll
        for (int j = 0; j < 4; ++j)
            bfr[j] = *(const bf16x8*)(ldsB + (wn + j * 16 + l16) * BK + ca);
        #pragma unroll
        for (int i = 0; i < 4; ++i)
            #pragma unroll
            for (int j = 0; j < 4; ++j)
                acc[i][j] = __builtin_amdgcn_mfma_f32_16x16x32_bf16(
                    bfr[j], af[i], acc[i][j], 0, 0, 0);
        __syncthreads();
    }

    const int sec   = colBase / secN;
    const int cbase = colBase - sec * secN;
    unsigned short*       Cs = (sec == 0) ? P.C0 : ((sec == 1) ? P.C1 : P.C2);
    const unsigned short* ad = (sec == 0) ? P.a0 : ((sec == 1) ? P.a1 : P.a2);
    const int*            gx = (sec == 0) ? P.x0 : ((sec == 1) ? P.x1 : P.x2);
    const float*          bs = (sec == 0) ? P.b0 : ((sec == 1) ? P.b1 : P.b2);

    f32x4 b4[4];
    #pragma unroll
    for (int j = 0; j < 4; ++j) {
        const int n0 = cbase + wn + j * 16 + quad * 4;
        b4[j] = bs ? *(const f32x4*)(bs + n0) : zv;
    }

    #pragma unroll
    for (int i = 0; i < 4; ++i) {
        const int row = rowBase + wm + i * 16 + l16;
        if (row >= M) continue;
        const int arow = gx ? gx[row] : row;
        const unsigned short* ar = ad ? ad + (size_t)arow * secN : nullptr;
        unsigned short* crow = Cs + (size_t)row * secN;
        #pragma unroll
        for (int j = 0; j < 4; ++j) {
            const int n0 = cbase + wn + j * 16 + quad * 4;
            f32x4 v = acc[i][j];
            v += b4[j];
            if (ar) {
                const us4v r4 = *(const us4v*)(ar + n0);
                #pragma unroll
                for (int r = 0; r < 4; ++r) v[r] += b2f(r4[r]);
            }
            if (relu) {
                #pragma unroll
                for (int r = 0; r < 4; ++r) v[r] = fmaxf(v[r], 0.0f);
            }
            us4v o4;
            #pragma unroll
            for (int r = 0; r < 4; ++r) o4[r] = f2b(v[r]);
            *(us4v*)(crow + n0) = o4;
        }
    }
}

// ---------------------------------------------------------------------------
// 256^2 GEMM, counted-vmcnt 2-deep pipeline (round-4, proven passing at
// 166 us / MfmaUtil 19.6% on edge QKV). BK=64, 8 waves, 128 KB LDS dbuf,
// vmcnt(8) counted waits + raw s_barrier. ONLY launched on grids >= ~700
// blocks (1 block/CU -> load balance dominates otherwise).
// ---------------------------------------------------------------------------
#define TM 256
#define TN 256
#define TK 64

__global__ __launch_bounds__(512, 1) void mfma_gemm256_kernel(
    const unsigned short* __restrict__ A, const unsigned short* __restrict__ Bt,
    GemmDst P, int M, int K, int N, int secN, int relu)
{
    __shared__ __align__(16) unsigned short ldsA[2][TM * TK];  // 2 x 32 KB
    __shared__ __align__(16) unsigned short ldsB[2][TN * TK];  // 2 x 32 KB

    // ---- panel-to-XCD swizzle ----
    const int nbx  = gridDim.x;
    const int nb   = nbx * gridDim.y;
    const int wgid = blockIdx.y * nbx + blockIdx.x;
    const int xcd  = wgid & 7;
    const int ii   = wgid >> 3;
    const int q8   = nb >> 3, r8 = nb & 7;
    const int base = (xcd < r8) ? xcd * (q8 + 1) : r8 * (q8 + 1) + (xcd - r8) * q8;
    const int tl   = base + ii;
    const int rowBase = (tl / nbx) * TM;
    const int colBase = (tl % nbx) * TN;

    const int tid  = threadIdx.x;           // 0..511
    const int lane = tid & 63;
    const int wave = tid >> 6;               // 0..7
    const int quad = lane >> 4;
    const int l16  = lane & 15;
    const int wr   = wave >> 2;              // 0..1 (M)
    const int wc   = wave & 3;               // 0..3 (N)

    // staging map: linear chunk p = j*512+tid (16 B), row r=p>>3, slot s=p&7,
    // slot holds global chunk c = s ^ (r&7) (involution, pre-swizzled source)
    const unsigned short* srcA[4];
    const unsigned short* srcB[4];
    int ldsOff[4];
    #pragma unroll
    for (int j = 0; j < 4; ++j) {
        const int p = j * 512 + tid;
        const int r = p >> 3;
        const int c = (p & 7) ^ (r & 7);
        ldsOff[j] = p * 8;
        int rA = rowBase + r; if (rA > M - 1) rA = M - 1;
        srcA[j] = A + (size_t)rA * K + c * 8;
        srcB[j] = Bt + (size_t)(colBase + r) * K + c * 8;
    }

    // read-side: global chunk q = ks*4+quad of row (..+l16) is at slot q^(l16&7)
    const int ca0 = (quad       ^ (l16 & 7)) * 8;
    const int ca1 = ((quad + 4) ^ (l16 & 7)) * 8;
    const int aRow0 = wr * 128 + l16;
    const int bRow0 = wc * 64 + l16;

    const f32x4 zv = {0.f, 0.f, 0.f, 0.f};
    f32x4 acc[8][4];
    #pragma unroll
    for (int i = 0; i < 8; ++i)
        #pragma unroll
        for (int j = 0; j < 4; ++j) acc[i][j] = zv;

#define STAGE256(buf, t)                                                      \
    {                                                                         \
        unsigned short* dA = ldsA[buf];                                       \
        unsigned short* dB = ldsB[buf];                                       \
        const int ko = (t) * TK;                                              \
        _Pragma("unroll")                                                     \
        for (int j = 0; j < 4; ++j)                                           \
            __builtin_amdgcn_global_load_lds(                                 \
                (const __attribute__((address_space(1))) void*)(srcA[j] + ko),\
                (__attribute__((address_space(3))) void*)(dA + ldsOff[j]),    \
                16, 0, 0);                                                    \
        _Pragma("unroll")                                                     \
        for (int j = 0; j < 4; ++j)                                           \
            __builtin_amdgcn_global_load_lds(                                 \
                (const __attribute__((address_space(1))) void*)(srcB[j] + ko),\
                (__attribute__((address_space(3))) void*)(dB + ldsOff[j]),    \
                16, 0, 0);                                                    \
    }

#define COMPUTE256(buf)                                                       \
    {                                                                         \
        const unsigned short* bA = ldsA[buf];                                 \
        const unsigned short* bB = ldsB[buf];                                 \
        _Pragma("unroll")                                                     \
        for (int ks = 0; ks < 2; ++ks) {                                      \
            const int cs = ks ? ca1 : ca0;                                    \
            bf16x8 afr[8], bfr[4];                                            \
            _Pragma("unroll")                                                 \
            for (int m = 0; m < 8; ++m)                                       \
                afr[m] = *(const bf16x8*)(bA + (aRow0 + m * 16) * TK + cs);   \
            _Pragma("unroll")                                                 \
            for (int n = 0; n < 4; ++n)                                       \
                bfr[n] = *(const bf16x8*)(bB + (bRow0 + n * 16) * TK + cs);   \
            _Pragma("unroll")                                                 \
            for (int m = 0; m < 8; ++m)                                       \
                _Pragma("unroll")                                             \
                for (int n = 0; n < 4; ++n)                                   \
                    acc[m][n] = __builtin_amdgcn_mfma_f32_16x16x32_bf16(      \
                        bfr[n], afr[m], acc[m][n], 0, 0, 0);                  \
        }                                                                     \
    }

    const int nt = K / TK;     // >= 2 at all call sites (K >= 512)

    // prologue: tiles 0,1 in flight (16 outstanding); wait tile 0 (own 8)
    STAGE256(0, 0);
    STAGE256(1, 1);
    asm volatile("s_waitcnt vmcnt(8)" ::: "memory");
    __builtin_amdgcn_s_barrier();
    __builtin_amdgcn_sched_barrier(0);

    for (int t = 0; t < nt - 2; ++t) {
        COMPUTE256(t & 1);
        __builtin_amdgcn_sched_barrier(0);
        __builtin_amdgcn_s_barrier();        // all waves done reading buf t&1
        STAGE256(t & 1, t + 2);              // overwrite; 16 outstanding
        asm volatile("s_waitcnt vmcnt(8)" ::: "memory");  // own t+1 landed
        __builtin_amdgcn_s_barrier();        // => all waves' t+1 landed
        __builtin_amdgcn_sched_barrier(0);
    }
    COMPUTE256(nt & 1);                      // tile nt-2 lives in buf (nt-2)&1
    __builtin_amdgcn_sched_barrier(0);
    asm volatile("s_waitcnt vmcnt(0)" ::: "memory");
    __builtin_amdgcn_s_barrier();
    __builtin_amdgcn_sched_barrier(0);
    COMPUTE256((nt - 1) & 1);

#undef STAGE256
#undef COMPUTE256

    const int sec   = colBase / secN;
    const int cbase = colBase - sec * secN;
    unsigned short*       Cs = (sec == 0) ? P.C0 : ((sec == 1) ? P.C1 : P.C2);
    const unsigned short* ad = (sec == 0) ? P.a0 : ((sec == 1) ? P.a1 : P.a2);
    const int*            gx = (sec == 0) ? P.x0 : ((sec == 1) ? P.x1 : P.x2);
    const float*          bs = (sec == 0) ? P.b0 : ((sec == 1) ? P.b1 : P.b2);

    f32x4 b4[4];
    #pragma unroll
    for (int n = 0; n < 4; ++n) {
        const int n0 = cbase + wc * 64 + n * 16 + quad * 4;
        b4[n] = bs ? *(const f32x4*)(bs + n0) : zv;
    }

    #pragma unroll
    for (int m = 0; m < 8; ++m) {
        const int row = rowBase + wr * 128 + m * 16 + l16;
        if (row >= M) continue;
        const int arow = gx ? gx[row] : row;
        const unsigned short* ar = ad ? ad + (size_t)arow * secN : nullptr;
        unsigned short* crow = Cs + (size_t)row * secN;
        #pragma unroll
        for (int n = 0; n < 4; ++n) {
            const int n0 = cbase + wc * 64 + n * 16 + quad * 4;
            f32x4 v = acc[m][n];
            v += b4[n];
            if (ar) {
                const us4v r4 = *(const us4v*)(ar + n0);
                #pragma unroll
                for (int r = 0; r < 4; ++r) v[r] += b2f(r4[r]);
            }
            if (relu) {
                #pragma unroll
                for (int r = 0; r < 4; ++r) v[r] = fmaxf(v[r], 0.0f);
            }
            us4v o4;
            #pragma unroll
            for (int r = 0; r < 4; ++r) o4[r] = f2b(v[r]);
            *(us4v*)(crow + n0) = o4;
        }
    }
}

// ---------------------------------------------------------------------------
// W[K][N] fp32 -> Wt[N][K] bf16
// ---------------------------------------------------------------------------
__global__ __launch_bounds__(256) void transpose_cast_kernel(
    const float* __restrict__ W, unsigned short* __restrict__ Wt, int K, int N)
{
    __shared__ float t[32][33];
    const int n0 = blockIdx.x << 5, k0 = blockIdx.y << 5;
    const int tx = threadIdx.x & 31, ty = threadIdx.x >> 5;
    #pragma unroll
    for (int r = 0; r < 32; r += 8)
        t[ty + r][tx] = W[(size_t)(k0 + ty + r) * N + n0 + tx];
    __syncthreads();
    #pragma unroll
    for (int r = 0; r < 32; r += 8)
        Wt[(size_t)(n0 + ty + r) * K + k0 + tx] = f2b(t[tx][ty + r]);
}

// ---------------------------------------------------------------------------
// LayerNorm in place over bf16 rows of width 512. One wave per row.
// ---------------------------------------------------------------------------
__global__ __launch_bounds__(256) void ln_kernel(
    unsigned short* __restrict__ x, const float* __restrict__ g,
    const float* __restrict__ b, int M)
{
    const int row = blockIdx.x * 4 + (threadIdx.x >> 6);
    if (row >= M) return;
    const int lane = threadIdx.x & 63;
    unsigned short* xr = x + (size_t)row * DMODEL;

    float vals[8];
    float s = 0.f, s2 = 0.f;
    #pragma unroll
    for (int i = 0; i < 8; ++i) {
        const float v = b2f(xr[lane + i * 64]);
        vals[i] = v; s += v; s2 += v * v;
    }
    #pragma unroll
    for (int o = 32; o > 0; o >>= 1) {
        s  += __shfl_down(s, o);
        s2 += __shfl_down(s2, o);
    }
    s  = __shfl(s, 0);
    s2 = __shfl(s2, 0);
    const float m = s * (1.0f / DMODEL);
    const float var = s2 * (1.0f / DMODEL) - m * m;
    const float r = rsqrtf(var + 1e-5f);
    #pragma unroll
    for (int i = 0; i < 8; ++i) {
        const int c = lane + i * 64;
        xr[c] = f2b((vals[i] - m) * r * g[c] + b[c]);
    }
}

// ---------------------------------------------------------------------------
// CSR build: histogram -> single-block scan -> scatter
// ---------------------------------------------------------------------------
__global__ __launch_bounds__(256) void hist_kernel(
    const int* __restrict__ dst, int* __restrict__ cnt, int ne)
{
    const int j = blockIdx.x * 256 + threadIdx.x;
    if (j < ne) atomicAdd(&cnt[dst[j]], 1);
}

__global__ __launch_bounds__(1024) void scan_kernel(
    const int* __restrict__ cnt, int* __restrict__ off,
    int* __restrict__ cur, int n)
{
    __shared__ int part[1024];
    const int t = threadIdx.x;
    const int chunk = (n + 1023) >> 10;
    const int lo = t * chunk;
    int hi = lo + chunk; if (hi > n) hi = n;
    int s = 0;
    for (int i = lo; i < hi; ++i) s += cnt[i];
    part[t] = s;
    __syncthreads();
    #pragma unroll
    for (int o = 1; o < 1024; o <<= 1) {
        int v = (t >= o) ? part[t - o] : 0;
        __syncthreads();
        part[t] += v;
        __syncthreads();
    }
    int base = (t == 0) ? 0 : part[t - 1];
    const int total = part[1023];
    for (int i = lo; i < hi; ++i) {
        const int c = cnt[i];
        off[i] = base; cur[i] = base;
        base += c;
    }
    if (t == 1023) off[n] = total;
}

__global__ __launch_bounds__(256) void scatter_kernel(
    const int* __restrict__ dst, int* __restrict__ cur,
    int* __restrict__ idx, int ne)
{
    const int j = blockIdx.x * 256 + threadIdx.x;
    if (j < ne) {
        const int p = atomicAdd(&cur[dst[j]], 1);
        idx[p] = j;
    }
}

// ---------------------------------------------------------------------------
// Fused CSR attention: ONE WAVE per destination segment (4 segs/block).
// No LDS, no barriers, q row loaded once; lane covers 8 contiguous cols,
// head = 8 lanes, score reduced with 3 xor-shuffles.
// ---------------------------------------------------------------------------
__global__ __launch_bounds__(256) void attend_kernel(
    unsigned short* __restrict__ q,
    const unsigned short* __restrict__ k,
    const unsigned short* __restrict__ v,
    const unsigned short* __restrict__ efeat,
    const int* __restrict__ src,
    const int* __restrict__ off, const int* __restrict__ idx,
    int nseg)
{
    const int wave = threadIdx.x >> 6, lane = threadIdx.x & 63;
    const int seg = blockIdx.x * 4 + wave;
    if (seg >= nseg) return;
    const int c8 = lane * 8;
    unsigned short* qrow = q + (size_t)seg * DMODEL;

    const us8v q8 = *(const us8v*)(qrow + c8);
    float qv[8];
    #pragma unroll
    for (int j = 0; j < 8; ++j) qv[j] = b2f(q8[j]);

    float acc[8] = {0.f, 0.f, 0.f, 0.f, 0.f, 0.f, 0.f, 0.f};
    float zsum = 0.f;
    const int lo = off[seg], hi = off[seg + 1];
    for (int jj = lo; jj < hi; ++jj) {
        const int e = idx[jj];
        const int s = src[e];
        const us8v k8 = *(const us8v*)(k + (size_t)s * DMODEL + c8);
        const us8v v8 = *(const us8v*)(v + (size_t)s * DMODEL + c8);
        float p = 0.f;
        float vv[8];
        if (efeat) {
            const us8v e8 = *(const us8v*)(efeat + (size_t)e * DMODEL + c8);
            #pragma unroll
            for (int j = 0; j < 8; ++j) {
                const float ef = b2f(e8[j]);
                p = fmaf(b2f(k8[j]) + ef, qv[j], p);
                vv[j] = b2f(v8[j]) + ef;
            }
        } else {
            #pragma unroll
            for (int j = 0; j < 8; ++j) {
                p = fmaf(b2f(k8[j]), qv[j], p);
                vv[j] = b2f(v8[j]);
            }
        }
        p += __shfl_xor(p, 1);
        p += __shfl_xor(p, 2);
        p += __shfl_xor(p, 4);
        float sc = p * 0.125f;                    // 1/sqrt(64)
        sc = fminf(fmaxf(sc, -10.0f), 10.0f);
        sc = __expf(sc);
        zsum += sc;
        #pragma unroll
        for (int j = 0; j < 8; ++j) acc[j] = fmaf(sc, vv[j], acc[j]);
    }

    const float rz = 1.0f / zsum;
    us8v o8;
    #pragma unroll
    for (int j = 0; j < 8; ++j) o8[j] = f2b(acc[j] * rz);
    *(us8v*)(qrow + c8) = o8;
}

// ---------------------------------------------------------------------------
__global__ __launch_bounds__(256) void gather_rel_kernel(
    const float* __restrict__ rel, const int* __restrict__ ef,
    unsigned short* __restrict__ lg)
{
    const int idx = blockIdx.x * 256 + threadIdx.x;
    if (idx >= NEDGES * DMODEL) return;
    const int e = idx >> 9;
    const int col = idx & 511;
    lg[idx] = f2b(rel[(size_t)ef[e] * DMODEL + col]);
}

__global__ __launch_bounds__(256) void cast_f2b_kernel(
    const float* __restrict__ in, unsigned short* __restrict__ out, int n)
{
    const int idx = blockIdx.x * 256 + threadIdx.x;
    if (idx < n) out[idx] = f2b(in[idx]);
}

__global__ __launch_bounds__(256) void cast_b2f_kernel(
    const unsigned short* __restrict__ in, float* __restrict__ out, int n)
{
    const int idx = blockIdx.x * 256 + threadIdx.x;
    if (idx < n) out[idx] = b2f(in[idx]);
}

__global__ __launch_bounds__(256) void zero_kernel(float4* __restrict__ p, int n4)
{
    const int idx = blockIdx.x * 256 + threadIdx.x;
    if (idx < n4) p[idx] = make_float4(0.f, 0.f, 0.f, 0.f);
}

// ---------------------------------------------------------------------------
static inline void mgemm(hipStream_t st, const unsigned short* A, const unsigned short* Bt,
                         const float* bias, const unsigned short* add, const int* gidx,
                         unsigned short* C, int M, int K, int N, int relu)
{
    GemmDst P = {C, nullptr, nullptr, add, nullptr, nullptr,
                 gidx, nullptr, nullptr, bias, nullptr, nullptr};
    dim3 g(N / BN, (M + BM - 1) / BM);
    mfma_gemm_kernel<<<g, 256, 0, st>>>(A, Bt, P, M, K, N, N, relu);
}

static inline void mgemm256(hipStream_t st, const unsigned short* A, const unsigned short* Bt,
                            const float* bias, const unsigned short* add, const int* gidx,
                            unsigned short* C, int M, int K, int N, int relu)
{
    GemmDst P = {C, nullptr, nullptr, add, nullptr, nullptr,
                 gidx, nullptr, nullptr, bias, nullptr, nullptr};
    dim3 g(N / TN, (M + TM - 1) / TM);
    mfma_gemm256_kernel<<<g, 512, 0, st>>>(A, Bt, P, M, K, N, N, relu);
}

static inline void mgemm_qkv(hipStream_t st, const unsigned short* A, const unsigned short* Bt,
                             const float* biasQ,
                             const unsigned short* addQ, const int* gxQ,
                             const unsigned short* addKV, const int* gxKV,
                             unsigned short* Cq, unsigned short* Ck, unsigned short* Cv,
                             int M, int K)
{
    GemmDst P = {Cq, Ck, Cv, addQ, addKV, addKV,
                 gxQ, gxKV, gxKV, biasQ, nullptr, nullptr};
    dim3 g(1536 / BN, (M + BM - 1) / BM);
    mfma_gemm_kernel<<<g, 256, 0, st>>>(A, Bt, P, M, K, 1536, 512, 0);
}

static inline void mgemm256_qkv(hipStream_t st, const unsigned short* A, const unsigned short* Bt,
                                const float* biasQ,
                                const unsigned short* addQ, const int* gxQ,
                                const unsigned short* addKV, const int* gxKV,
                                unsigned short* Cq, unsigned short* Ck, unsigned short* Cv,
                                int M, int K)
{
    GemmDst P = {Cq, Ck, Cv, addQ, addKV, addKV,
                 gxQ, gxKV, gxKV, biasQ, nullptr, nullptr};
    dim3 g(1536 / TN, (M + TM - 1) / TM);
    mfma_gemm256_kernel<<<g, 512, 0, st>>>(A, Bt, P, M, K, 1536, 512, 0);
}

static inline void tcast(hipStream_t st, const float* W, unsigned short* Wt, int K, int N)
{
    dim3 g(N / 32, K / 32);
    transpose_cast_kernel<<<g, 256, 0, st>>>(W, Wt, K, N);
}
static inline void zero(hipStream_t st, void* p, size_t nfloats)
{
    const int n4 = (int)(nfloats / 4);
    zero_kernel<<<(n4 + 255) / 256, 256, 0, st>>>((float4*)p, n4);
}

extern "C" void kernel_launch(void* const* d_in, const int* in_sizes, int n_in,
                              void* d_out, int out_size, void* d_ws, size_t ws_size,
                              hipStream_t stream)
{
    const float* x_in      = (const float*)d_in[0];
    const int*   edge_feat = (const int*)d_in[1];
    const int*   src_ids   = (const int*)d_in[2];
    const int*   dst_ids   = (const int*)d_in[3];
    const int*   lg_src    = (const int*)d_in[4];
    const int*   lg_dst    = (const int*)d_in[5];
    const float* rel_embed = (const float*)d_in[6];

    const float* n_Wq = (const float*)d_in[7];   const float* n_bq = (const float*)d_in[8];
    const float* n_Wk = (const float*)d_in[9];   const float* n_Wv = (const float*)d_in[10];
    const float* n_Wo = (const float*)d_in[11];  const float* n_bo = (const float*)d_in[12];
    const float* n_lg = (const float*)d_in[13];  const float* n_lb = (const float*)d_in[14];
    const float* n_f1 = (const float*)d_in[15];  const float* n_fb1 = (const float*)d_in[16];
    const float* n_f2 = (const float*)d_in[17];  const float* n_fb2 = (const float*)d_in[18];
    const float* n_fg = (const float*)d_in[19];  const float* n_fb = (const float*)d_in[20];

    const float* e_Wq = (const float*)d_in[21];  const float* e_bq = (const float*)d_in[22];
    const float* e_Wk = (const float*)d_in[23];  const float* e_Wv = (const float*)d_in[24];
    const float* e_Wo = (const float*)d_in[25];  const float* e_bo = (const float*)d_in[26];
    const float* e_lg = (const float*)d_in[27];  const float* e_lb = (const float*)d_in[28];
    const float* e_f1 = (const float*)d_in[29];  const float* e_fb1 = (const float*)d_in[30];
    const float* e_f2 = (const float*)d_in[31];  const float* e_fb2 = (const float*)d_in[32];
    const float* e_fg = (const float*)d_in[33];  const float* e_fb = (const float*)d_in[34];

    const int XSZ  = NNODES * DMODEL;
    const int LGSZ = NEDGES * DMODEL;

    // ---- workspace layout ---------------------------------------------------
    char* ws = (char*)d_ws;
    unsigned short* lg16  = (unsigned short*)(ws);               // 51,200,000 B
    unsigned short* ve16  = (unsigned short*)(ws + 51200000);    // 51,200,000 B
    int* n_off = (int*)(ws + 102400000);
    int* n_cur = (int*)(ws + 102420480);
    int* n_idx = (int*)(ws + 102440960);
    int* e_off = (int*)(ws + 102641664);
    int* e_cur = (int*)(ws + 102842368);
    int* e_idx = (int*)(ws + 103043072);                         // ends 103.84 MB
    unsigned short* xbufA = (unsigned short*)(ws + 110400000);   // 5,120,000 B
    unsigned short* xbufB = (unsigned short*)(ws + 115520000);   // 5,120,000 B

    // ---- d_out scratch (112.64 MB) -----------------------------------------
    char* ob = (char*)d_out;
    unsigned short* qe16 = (unsigned short*)(ob);                // 51.2 MB
    unsigned short* ke16 = (unsigned short*)(ob + 51200000);     // 51.2 MB
    unsigned short* ehid = (unsigned short*)(ob);                // 102.4 MB (edge FFN hidden; qe/ke dead then)
    unsigned short* nq16 = (unsigned short*)(ob);
    unsigned short* nk16 = (unsigned short*)(ob + 5120000);
    unsigned short* nv16 = (unsigned short*)(ob + 10240000);
    unsigned short* nhid = (unsigned short*)(ob);                // 20.48 MB
    unsigned short* wtq  = (unsigned short*)(ob + 102400000);    // q|k|v contiguous
    unsigned short* wtk  = (unsigned short*)(ob + 102924288);
    unsigned short* wtv  = (unsigned short*)(ob + 103448576);
    unsigned short* wto  = (unsigned short*)(ob + 103972864);
    unsigned short* wtf1 = (unsigned short*)(ob + 104497152);    // 2 MB
    unsigned short* wtf2 = (unsigned short*)(ob + 106594304);    // 2 MB (ends 108.7 MB)

    // ---- init + CSR build ---------------------------------------------------
    cast_f2b_kernel<<<(XSZ + 255) / 256, 256, 0, stream>>>(x_in, xbufA, XSZ);
    gather_rel_kernel<<<(LGSZ + 255) / 256, 256, 0, stream>>>(rel_embed, edge_feat, lg16);

    zero(stream, n_cur, NNODES);
    zero(stream, e_cur, NEDGES);
    hist_kernel<<<(NEDGES + 255) / 256, 256, 0, stream>>>(dst_ids, n_cur, NEDGES);
    hist_kernel<<<(NELG + 255) / 256, 256, 0, stream>>>(lg_dst, e_cur, NELG);
    scan_kernel<<<1, 1024, 0, stream>>>(n_cur, n_off, n_cur, NNODES);
    scan_kernel<<<1, 1024, 0, stream>>>(e_cur, e_off, e_cur, NEDGES);
    scatter_kernel<<<(NEDGES + 255) / 256, 256, 0, stream>>>(dst_ids, n_cur, n_idx, NEDGES);
    scatter_kernel<<<(NELG + 255) / 256, 256, 0, stream>>>(lg_dst, e_cur, e_idx, NELG);

    unsigned short* xc = xbufA;
    unsigned short* xn = xbufB;

    for (int i = 0; i < NLAYERS; ++i) {
        const size_t wo  = (size_t)i * DMODEL * DMODEL;
        const size_t bo_ = (size_t)i * DMODEL;
        const size_t f1o = (size_t)i * DMODEL * 4 * DMODEL;
        const size_t b1o = (size_t)i * 4 * DMODEL;
        const size_t f2o = (size_t)i * 4 * DMODEL * DMODEL;

        // ================= node update (reads xc, lg16) =================
        tcast(stream, n_Wq + wo, wtq, 512, 512);
        tcast(stream, n_Wk + wo, wtk, 512, 512);
        tcast(stream, n_Wv + wo, wtv, 512, 512);
        tcast(stream, n_Wo + wo, wto, 512, 512);
        tcast(stream, n_f1 + f1o, wtf1, 512, 2048);
        tcast(stream, n_f2 + f2o, wtf2, 2048, 512);

        mgemm_qkv(stream, xc, wtq, n_bq + bo_,
                  nullptr, nullptr, nullptr, nullptr,
                  nq16, nk16, nv16, NNODES, 512);

        attend_kernel<<<(NNODES + 3) / 4, 256, 0, stream>>>(
            nq16, nk16, nv16, lg16, src_ids, n_off, n_idx, NNODES);

        mgemm(stream, nq16, wto, n_bo + bo_, xc, nullptr, xn, NNODES, 512, 512, 0);
        ln_kernel<<<(NNODES + 3) / 4, 256, 0, stream>>>(xn, n_lg + bo_, n_lb + bo_, NNODES);
        mgemm(stream, xn, wtf1, n_fb1 + b1o, nullptr, nullptr, nhid, NNODES, 512, 2048, 1);
        mgemm(stream, nhid, wtf2, n_fb2 + bo_, xn, nullptr, xn, NNODES, 2048, 512, 0);
        ln_kernel<<<(NNODES + 3) / 4, 256, 0, stream>>>(xn, n_fg + bo_, n_fb + bo_, NNODES);

        // ================= edge update (reads PRE-update xc) =================
        tcast(stream, e_Wq + wo, wtq, 512, 512);
        tcast(stream, e_Wk + wo, wtk, 512, 512);
        tcast(stream, e_Wv + wo, wtv, 512, 512);
        tcast(stream, e_Wo + wo, wto, 512, 512);

        mgemm256_qkv(stream, lg16, wtq, e_bq + bo_,
                     xc, dst_ids, xc, src_ids,
                     qe16, ke16, ve16, NEDGES, 512);

        attend_kernel<<<(NEDGES + 3) / 4, 256, 0, stream>>>(
            qe16, ke16, ve16, nullptr, lg_src, e_off, e_idx, NEDGES);

        mgemm(stream, qe16, wto, e_bo + bo_, lg16, nullptr, lg16, NEDGES, 512, 512, 0);
        ln_kernel<<<(NEDGES + 3) / 4, 256, 0, stream>>>(lg16, e_lg + bo_, e_lb + bo_, NEDGES);

        // qe16/ke16 dead now -> 102.4 MB hidden buffer, 2 chunks of 25000
        tcast(stream, e_f1 + f1o, wtf1, 512, 2048);
        tcast(stream, e_f2 + f2o, wtf2, 2048, 512);
        for (int c = 0; c < 2; ++c) {
            unsigned short* y1c = lg16 + (size_t)c * 25000 * DMODEL;
            mgemm256(stream, y1c, wtf1, e_fb1 + b1o, nullptr, nullptr, ehid, 25000, 512, 2048, 1);
            mgemm(stream, ehid, wtf2, e_fb2 + bo_, y1c, nullptr, y1c, 25000, 2048, 512, 0);
        }
        ln_kernel<<<(NEDGES + 3) / 4, 256, 0, stream>>>(lg16, e_fg + bo_, e_fb + bo_, NEDGES);

        unsigned short* t = xc; xc = xn; xn = t;
    }

    // final: bf16 -> fp32 d_out (all d_out scratch dead now)
    float* out_f = (float*)d_out;
    cast_b2f_kernel<<<(XSZ + 255) / 256, 256, 0, stream>>>(xc, out_f, XSZ);
    cast_b2f_kernel<<<(LGSZ + 255) / 256, 256, 0, stream>>>(lg16, out_f + XSZ, LGSZ);
}

// Round 8
// 2258.822 us; speedup vs baseline: 1.0811x; 1.0050x over previous
//
#include <hip/hip_runtime.h>
#include <math.h>

#define NNODES 5000
#define NEDGES 50000
#define NELG   200000
#define DMODEL 512
#define NH     8
#define NLAYERS 2

typedef __bf16 bf16x8 __attribute__((ext_vector_type(8)));
typedef float  f32x4  __attribute__((ext_vector_type(4)));
typedef unsigned short us8v __attribute__((ext_vector_type(8)));
typedef unsigned short us4v __attribute__((ext_vector_type(4)));

// ---- bf16 helpers (stored as unsigned short) ------------------------------
__device__ __forceinline__ float b2f(unsigned short u) {
    union { unsigned int i; float f; } c;
    c.i = ((unsigned int)u) << 16;
    return c.f;
}
__device__ __forceinline__ unsigned short f2b(float f) {
    union { float f; unsigned int i; } c;
    c.f = f;
    unsigned int i = c.i;
    return (unsigned short)((i + 0x7fffu + ((i >> 16) & 1u)) >> 16);
}

struct GemmDst {
    unsigned short* C0; unsigned short* C1; unsigned short* C2;
    const unsigned short* a0; const unsigned short* a1; const unsigned short* a2;
    const int* x0; const int* x1; const int* x2;
    const float* b0; const float* b1; const float* b2;
};

// ---------------------------------------------------------------------------
// 128^2 GEMM (round-3, proven): BK=32, 16 KB LDS, __syncthreads, XCD panel
// swizzle, swapped-operand MFMA -> vectorized D^T epilogue. 8 blocks/CU.
// ---------------------------------------------------------------------------
#define BM 128
#define BN 128
#define BK 32

__global__ __launch_bounds__(256) void mfma_gemm_kernel(
    const unsigned short* __restrict__ A, const unsigned short* __restrict__ Bt,
    GemmDst P, int M, int K, int N, int secN, int relu)
{
    __shared__ __align__(16) unsigned short ldsA[BM * BK];  // 8 KB
    __shared__ __align__(16) unsigned short ldsB[BN * BK];  // 8 KB

    // ---- panel-to-XCD swizzle (bijective remap, dispatch wgid%8 = XCD) ----
    const int nbx  = gridDim.x;
    const int nb   = nbx * gridDim.y;
    const int wgid = blockIdx.y * nbx + blockIdx.x;
    const int xcd  = wgid & 7;
    const int ii   = wgid >> 3;
    const int q8   = nb >> 3, r8 = nb & 7;
    const int base = (xcd < r8) ? xcd * (q8 + 1) : r8 * (q8 + 1) + (xcd - r8) * q8;
    const int tl   = base + ii;
    const int rowBase = (tl / nbx) * BM;
    const int colBase = (tl % nbx) * BN;

    const int tid  = threadIdx.x;
    const int lane = tid & 63;
    const int wave = tid >> 6;
    const int quad = lane >> 4;
    const int l16  = lane & 15;
    const int wm = (wave >> 1) * 64;
    const int wn = (wave & 1) * 64;

    const int g0 = tid, g1 = tid + 256;
    const int r0 = g0 >> 2, r1 = g1 >> 2;
    const int c0g = (g0 & 3) ^ ((r0 >> 1) & 3);
    const int c1g = (g1 & 3) ^ ((r1 >> 1) & 3);
    int ra0 = rowBase + r0; if (ra0 > M - 1) ra0 = M - 1;
    int ra1 = rowBase + r1; if (ra1 > M - 1) ra1 = M - 1;
    const unsigned short* gA0 = A + (size_t)ra0 * K + c0g * 8;
    const unsigned short* gA1 = A + (size_t)ra1 * K + c1g * 8;
    const unsigned short* gB0 = Bt + (size_t)(colBase + r0) * K + c0g * 8;
    const unsigned short* gB1 = Bt + (size_t)(colBase + r1) * K + c1g * 8;
    unsigned short* lA0 = ldsA + g0 * 8;
    unsigned short* lA1 = ldsA + g1 * 8;
    unsigned short* lB0 = ldsB + g0 * 8;
    unsigned short* lB1 = ldsB + g1 * 8;

    const int swz = (l16 >> 1) & 3;
    const int ca = (quad ^ swz) * 8;

    const f32x4 zv = {0.f, 0.f, 0.f, 0.f};
    f32x4 acc[4][4];
    #pragma unroll
    for (int i = 0; i < 4; ++i)
        #pragma unroll
        for (int j = 0; j < 4; ++j) acc[i][j] = zv;

    for (int k0 = 0; k0 < K; k0 += BK) {
        __builtin_amdgcn_global_load_lds(
            (const __attribute__((address_space(1))) void*)(gA0 + k0),
            (__attribute__((address_space(3))) void*)lA0, 16, 0, 0);
        __builtin_amdgcn_global_load_lds(
            (const __attribute__((address_space(1))) void*)(gA1 + k0),
            (__attribute__((address_space(3))) void*)lA1, 16, 0, 0);
        __builtin_amdgcn_global_load_lds(
            (const __attribute__((address_space(1))) void*)(gB0 + k0),
            (__attribute__((address_space(3))) void*)lB0, 16, 0, 0);
        __builtin_amdgcn_global_load_lds(
            (const __attribute__((address_space(1))) void*)(gB1 + k0),
            (__attribute__((address_space(3))) void*)lB1, 16, 0, 0);
        __syncthreads();

        bf16x8 af[4], bfr[4];
        #pragma unroll
        for (int i = 0; i < 4; ++i)
            af[i] = *(const bf16x8*)(ldsA + (wm + i * 16 + l16) * BK + ca);
        #pragma unroll
        for (int j = 0; j < 4; ++j)
            bfr[j] = *(const bf16x8*)(ldsB + (wn + j * 16 + l16) * BK + ca);
        #pragma unroll
        for (int i = 0; i < 4; ++i)
            #pragma unroll
            for (int j = 0; j < 4; ++j)
                acc[i][j] = __builtin_amdgcn_mfma_f32_16x16x32_bf16(
                    bfr[j], af[i], acc[i][j], 0, 0, 0);
        __syncthreads();
    }

    const int sec   = colBase / secN;
    const int cbase = colBase - sec * secN;
    unsigned short*       Cs = (sec == 0) ? P.C0 : ((sec == 1) ? P.C1 : P.C2);
    const unsigned short* ad = (sec == 0) ? P.a0 : ((sec == 1) ? P.a1 : P.a2);
    const int*            gx = (sec == 0) ? P.x0 : ((sec == 1) ? P.x1 : P.x2);
    const float*          bs = (sec == 0) ? P.b0 : ((sec == 1) ? P.b1 : P.b2);

    f32x4 b4[4];
    #pragma unroll
    for (int j = 0; j < 4; ++j) {
        const int n0 = cbase + wn + j * 16 + quad * 4;
        b4[j] = bs ? *(const f32x4*)(bs + n0) : zv;
    }

    #pragma unroll
    for (int i = 0; i < 4; ++i) {
        const int row = rowBase + wm + i * 16 + l16;
        if (row >= M) continue;
        const int arow = gx ? gx[row] : row;
        const unsigned short* ar = ad ? ad + (size_t)arow * secN : nullptr;
        unsigned short* crow = Cs + (size_t)row * secN;
        #pragma unroll
        for (int j = 0; j < 4; ++j) {
            const int n0 = cbase + wn + j * 16 + quad * 4;
            f32x4 v = acc[i][j];
            v += b4[j];
            if (ar) {
                const us4v r4 = *(const us4v*)(ar + n0);
                #pragma unroll
                for (int r = 0; r < 4; ++r) v[r] += b2f(r4[r]);
            }
            if (relu) {
                #pragma unroll
                for (int r = 0; r < 4; ++r) v[r] = fmaxf(v[r], 0.0f);
            }
            us4v o4;
            #pragma unroll
            for (int r = 0; r < 4; ++r) o4[r] = f2b(v[r]);
            *(us4v*)(crow + n0) = o4;
        }
    }
}

// ---------------------------------------------------------------------------
// 256^2 GEMM, 4-phase-per-K-tile schedule (m201-style port). Per phase:
// {ds_read subtile || stage 2 gload_lds of tile t+1 -> s_barrier ->
//  setprio(1) -> 16 MFMA -> setprio(0) -> s_barrier}. One vmcnt(0) per
// tile boundary (2-buffer depth). Register ceiling (128 AGPR acc) caps
// this tile at 8 waves/CU -> intra-block overlap is the only lever.
// Hazards: reads touch buf cur (landed at prev boundary); stages write buf
// nxt whose readers passed the boundary barrier. Same XOR swizzle + D^T
// epilogue as round-6 (proven). Grids >= ~700 blocks only.
// ---------------------------------------------------------------------------
#define TM 256
#define TN 256
#define TK 64

__global__ __launch_bounds__(512, 1) void mfma_gemm256_kernel(
    const unsigned short* __restrict__ A, const unsigned short* __restrict__ Bt,
    GemmDst P, int M, int K, int N, int secN, int relu)
{
    __shared__ __align__(16) unsigned short ldsA[2][TM * TK];  // 2 x 32 KB
    __shared__ __align__(16) unsigned short ldsB[2][TN * TK];  // 2 x 32 KB

    // ---- panel-to-XCD swizzle ----
    const int nbx  = gridDim.x;
    const int nb   = nbx * gridDim.y;
    const int wgid = blockIdx.y * nbx + blockIdx.x;
    const int xcd  = wgid & 7;
    const int ii   = wgid >> 3;
    const int q8   = nb >> 3, r8 = nb & 7;
    const int base = (xcd < r8) ? xcd * (q8 + 1) : r8 * (q8 + 1) + (xcd - r8) * q8;
    const int tl   = base + ii;
    const int rowBase = (tl / nbx) * TM;
    const int colBase = (tl % nbx) * TN;

    const int tid  = threadIdx.x;           // 0..511
    const int lane = tid & 63;
    const int wave = tid >> 6;               // 0..7
    const int quad = lane >> 4;
    const int l16  = lane & 15;
    const int wr   = wave >> 2;              // 0..1 (M)
    const int wc   = wave & 3;               // 0..3 (N)

    // staging map: linear chunk p = j*512+tid (16 B), row r=p>>3, slot s=p&7,
    // slot holds global chunk c = s ^ (r&7) (involution, pre-swizzled source)
    const unsigned short* srcA[4];
    const unsigned short* srcB[4];
    int ldsOff[4];
    #pragma unroll
    for (int j = 0; j < 4; ++j) {
        const int p = j * 512 + tid;
        const int r = p >> 3;
        const int c = (p & 7) ^ (r & 7);
        ldsOff[j] = p * 8;
        int rA = rowBase + r; if (rA > M - 1) rA = M - 1;
        srcA[j] = A + (size_t)rA * K + c * 8;
        srcB[j] = Bt + (size_t)(colBase + r) * K + c * 8;
    }

    // read-side: global chunk q = ks*4+quad of row (..+l16) is at slot q^(l16&7)
    const int ca0 = (quad       ^ (l16 & 7)) * 8;
    const int ca1 = ((quad + 4) ^ (l16 & 7)) * 8;
    const int aRow0 = wr * 128 + l16;
    const int bRow0 = wc * 64 + l16;

    const f32x4 zv = {0.f, 0.f, 0.f, 0.f};
    f32x4 acc[8][4];
    #pragma unroll
    for (int i = 0; i < 8; ++i)
        #pragma unroll
        for (int j = 0; j < 4; ++j) acc[i][j] = zv;

#define STG2(dst, src, kn, j0)                                                \
    {                                                                         \
        _Pragma("unroll")                                                     \
        for (int j = (j0); j < (j0) + 2; ++j)                                 \
            __builtin_amdgcn_global_load_lds(                                 \
                (const __attribute__((address_space(1))) void*)((src)[j] + (kn)), \
                (__attribute__((address_space(3))) void*)((dst) + ldsOff[j]), \
                16, 0, 0);                                                    \
    }

    // one phase: ds_read subtile, stage, align-barrier, prio-MFMA cluster
#define PHASE(CS, MBASE, READB, STG)                                          \
    {                                                                         \
        _Pragma("unroll")                                                     \
        for (int m = 0; m < 4; ++m)                                           \
            afr[m] = *(const bf16x8*)(bA + (aRow0 + ((MBASE) + m) * 16) * TK + (CS)); \
        if (READB) {                                                          \
            _Pragma("unroll")                                                 \
            for (int n = 0; n < 4; ++n)                                       \
                bfr[n] = *(const bf16x8*)(bB + (bRow0 + n * 16) * TK + (CS)); \
        }                                                                     \
        STG;                                                                  \
        __builtin_amdgcn_s_barrier();                                         \
        __builtin_amdgcn_sched_barrier(0);                                    \
        __builtin_amdgcn_s_setprio(1);                                        \
        _Pragma("unroll")                                                     \
        for (int m = 0; m < 4; ++m)                                           \
            _Pragma("unroll")                                                 \
            for (int n = 0; n < 4; ++n)                                       \
                acc[(MBASE) + m][n] = __builtin_amdgcn_mfma_f32_16x16x32_bf16(\
                    bfr[n], afr[m], acc[(MBASE) + m][n], 0, 0, 0);            \
        __builtin_amdgcn_s_setprio(0);                                        \
        __builtin_amdgcn_sched_barrier(0);                                    \
    }

    const int nt = K / TK;     // >= 2 at all call sites (K >= 512)

    // prologue: tile 0 -> buf 0, drain, barrier
    STG2(ldsA[0], srcA, 0, 0); STG2(ldsA[0], srcA, 0, 2);
    STG2(ldsB[0], srcB, 0, 0); STG2(ldsB[0], srcB, 0, 2);
    asm volatile("s_waitcnt vmcnt(0)" ::: "memory");
    __builtin_amdgcn_s_barrier();
    __builtin_amdgcn_sched_barrier(0);

    for (int t = 0; t < nt; ++t) {
        const int cur = t & 1;
        const unsigned short* bA = ldsA[cur];
        const unsigned short* bB = ldsB[cur];
        unsigned short* dA = ldsA[cur ^ 1];
        unsigned short* dB = ldsB[cur ^ 1];
        const bool pf = (t + 1 < nt);
        const int kn = (t + 1) * TK;
        bf16x8 afr[4], bfr[4];

        // phase 0: ks0, m0-3 (+B reads) | stage A half 0
        PHASE(ca0, 0, 1, if (pf) STG2(dA, srcA, kn, 0));
        __builtin_amdgcn_s_barrier();
        // phase 1: ks0, m4-7 (bfr persists) | stage A half 1
        PHASE(ca0, 4, 0, if (pf) STG2(dA, srcA, kn, 2));
        __builtin_amdgcn_s_barrier();
        // phase 2: ks1, m0-3 (+B reads) | stage B half 0
        PHASE(ca1, 0, 1, if (pf) STG2(dB, srcB, kn, 0));
        __builtin_amdgcn_s_barrier();
        // phase 3: ks1, m4-7 | stage B half 1; tile boundary drain
        PHASE(ca1, 4, 0, if (pf) STG2(dB, srcB, kn, 2));
        if (pf) asm volatile("s_waitcnt vmcnt(0)" ::: "memory");
        __builtin_amdgcn_s_barrier();
        __builtin_amdgcn_sched_barrier(0);
    }

#undef PHASE
#undef STG2

    const int sec   = colBase / secN;
    const int cbase = colBase - sec * secN;
    unsigned short*       Cs = (sec == 0) ? P.C0 : ((sec == 1) ? P.C1 : P.C2);
    const unsigned short* ad = (sec == 0) ? P.a0 : ((sec == 1) ? P.a1 : P.a2);
    const int*            gx = (sec == 0) ? P.x0 : ((sec == 1) ? P.x1 : P.x2);
    const float*          bs = (sec == 0) ? P.b0 : ((sec == 1) ? P.b1 : P.b2);

    f32x4 b4[4];
    #pragma unroll
    for (int n = 0; n < 4; ++n) {
        const int n0 = cbase + wc * 64 + n * 16 + quad * 4;
        b4[n] = bs ? *(const f32x4*)(bs + n0) : zv;
    }

    #pragma unroll
    for (int m = 0; m < 8; ++m) {
        const int row = rowBase + wr * 128 + m * 16 + l16;
        if (row >= M) continue;
        const int arow = gx ? gx[row] : row;
        const unsigned short* ar = ad ? ad + (size_t)arow * secN : nullptr;
        unsigned short* crow = Cs + (size_t)row * secN;
        #pragma unroll
        for (int n = 0; n < 4; ++n) {
            const int n0 = cbase + wc * 64 + n * 16 + quad * 4;
            f32x4 v = acc[m][n];
            v += b4[n];
            if (ar) {
                const us4v r4 = *(const us4v*)(ar + n0);
                #pragma unroll
                for (int r = 0; r < 4; ++r) v[r] += b2f(r4[r]);
            }
            if (relu) {
                #pragma unroll
                for (int r = 0; r < 4; ++r) v[r] = fmaxf(v[r], 0.0f);
            }
            us4v o4;
            #pragma unroll
            for (int r = 0; r < 4; ++r) o4[r] = f2b(v[r]);
            *(us4v*)(crow + n0) = o4;
        }
    }
}

// ---------------------------------------------------------------------------
// W[K][N] fp32 -> Wt[N][K] bf16
// ---------------------------------------------------------------------------
__global__ __launch_bounds__(256) void transpose_cast_kernel(
    const float* __restrict__ W, unsigned short* __restrict__ Wt, int K, int N)
{
    __shared__ float t[32][33];
    const int n0 = blockIdx.x << 5, k0 = blockIdx.y << 5;
    const int tx = threadIdx.x & 31, ty = threadIdx.x >> 5;
    #pragma unroll
    for (int r = 0; r < 32; r += 8)
        t[ty + r][tx] = W[(size_t)(k0 + ty + r) * N + n0 + tx];
    __syncthreads();
    #pragma unroll
    for (int r = 0; r < 32; r += 8)
        Wt[(size_t)(n0 + ty + r) * K + k0 + tx] = f2b(t[tx][ty + r]);
}

// ---------------------------------------------------------------------------
// LayerNorm in place over bf16 rows of width 512. One wave per row.
// ---------------------------------------------------------------------------
__global__ __launch_bounds__(256) void ln_kernel(
    unsigned short* __restrict__ x, const float* __restrict__ g,
    const float* __restrict__ b, int M)
{
    const int row = blockIdx.x * 4 + (threadIdx.x >> 6);
    if (row >= M) return;
    const int lane = threadIdx.x & 63;
    unsigned short* xr = x + (size_t)row * DMODEL;

    float vals[8];
    float s = 0.f, s2 = 0.f;
    #pragma unroll
    for (int i = 0; i < 8; ++i) {
        const float v = b2f(xr[lane + i * 64]);
        vals[i] = v; s += v; s2 += v * v;
    }
    #pragma unroll
    for (int o = 32; o > 0; o >>= 1) {
        s  += __shfl_down(s, o);
        s2 += __shfl_down(s2, o);
    }
    s  = __shfl(s, 0);
    s2 = __shfl(s2, 0);
    const float m = s * (1.0f / DMODEL);
    const float var = s2 * (1.0f / DMODEL) - m * m;
    const float r = rsqrtf(var + 1e-5f);
    #pragma unroll
    for (int i = 0; i < 8; ++i) {
        const int c = lane + i * 64;
        xr[c] = f2b((vals[i] - m) * r * g[c] + b[c]);
    }
}

// ---------------------------------------------------------------------------
// CSR build: histogram -> single-block scan -> scatter
// ---------------------------------------------------------------------------
__global__ __launch_bounds__(256) void hist_kernel(
    const int* __restrict__ dst, int* __restrict__ cnt, int ne)
{
    const int j = blockIdx.x * 256 + threadIdx.x;
    if (j < ne) atomicAdd(&cnt[dst[j]], 1);
}

__global__ __launch_bounds__(1024) void scan_kernel(
    const int* __restrict__ cnt, int* __restrict__ off,
    int* __restrict__ cur, int n)
{
    __shared__ int part[1024];
    const int t = threadIdx.x;
    const int chunk = (n + 1023) >> 10;
    const int lo = t * chunk;
    int hi = lo + chunk; if (hi > n) hi = n;
    int s = 0;
    for (int i = lo; i < hi; ++i) s += cnt[i];
    part[t] = s;
    __syncthreads();
    #pragma unroll
    for (int o = 1; o < 1024; o <<= 1) {
        int v = (t >= o) ? part[t - o] : 0;
        __syncthreads();
        part[t] += v;
        __syncthreads();
    }
    int base = (t == 0) ? 0 : part[t - 1];
    const int total = part[1023];
    for (int i = lo; i < hi; ++i) {
        const int c = cnt[i];
        off[i] = base; cur[i] = base;
        base += c;
    }
    if (t == 1023) off[n] = total;
}

__global__ __launch_bounds__(256) void scatter_kernel(
    const int* __restrict__ dst, int* __restrict__ cur,
    int* __restrict__ idx, int ne)
{
    const int j = blockIdx.x * 256 + threadIdx.x;
    if (j < ne) {
        const int p = atomicAdd(&cur[dst[j]], 1);
        idx[p] = j;
    }
}

// ---------------------------------------------------------------------------
// Fused CSR attention: ONE WAVE per destination segment (4 segs/block).
// ---------------------------------------------------------------------------
__global__ __launch_bounds__(256) void attend_kernel(
    unsigned short* __restrict__ q,
    const unsigned short* __restrict__ k,
    const unsigned short* __restrict__ v,
    const unsigned short* __restrict__ efeat,
    const int* __restrict__ src,
    const int* __restrict__ off, const int* __restrict__ idx,
    int nseg)
{
    const int wave = threadIdx.x >> 6, lane = threadIdx.x & 63;
    const int seg = blockIdx.x * 4 + wave;
    if (seg >= nseg) return;
    const int c8 = lane * 8;
    unsigned short* qrow = q + (size_t)seg * DMODEL;

    const us8v q8 = *(const us8v*)(qrow + c8);
    float qv[8];
    #pragma unroll
    for (int j = 0; j < 8; ++j) qv[j] = b2f(q8[j]);

    float acc[8] = {0.f, 0.f, 0.f, 0.f, 0.f, 0.f, 0.f, 0.f};
    float zsum = 0.f;
    const int lo = off[seg], hi = off[seg + 1];
    for (int jj = lo; jj < hi; ++jj) {
        const int e = idx[jj];
        const int s = src[e];
        const us8v k8 = *(const us8v*)(k + (size_t)s * DMODEL + c8);
        const us8v v8 = *(const us8v*)(v + (size_t)s * DMODEL + c8);
        float p = 0.f;
        float vv[8];
        if (efeat) {
            const us8v e8 = *(const us8v*)(efeat + (size_t)e * DMODEL + c8);
            #pragma unroll
            for (int j = 0; j < 8; ++j) {
                const float ef = b2f(e8[j]);
                p = fmaf(b2f(k8[j]) + ef, qv[j], p);
                vv[j] = b2f(v8[j]) + ef;
            }
        } else {
            #pragma unroll
            for (int j = 0; j < 8; ++j) {
                p = fmaf(b2f(k8[j]), qv[j], p);
                vv[j] = b2f(v8[j]);
            }
        }
        p += __shfl_xor(p, 1);
        p += __shfl_xor(p, 2);
        p += __shfl_xor(p, 4);
        float sc = p * 0.125f;                    // 1/sqrt(64)
        sc = fminf(fmaxf(sc, -10.0f), 10.0f);
        sc = __expf(sc);
        zsum += sc;
        #pragma unroll
        for (int j = 0; j < 8; ++j) acc[j] = fmaf(sc, vv[j], acc[j]);
    }

    const float rz = 1.0f / zsum;
    us8v o8;
    #pragma unroll
    for (int j = 0; j < 8; ++j) o8[j] = f2b(acc[j] * rz);
    *(us8v*)(qrow + c8) = o8;
}

// ---------------------------------------------------------------------------
__global__ __launch_bounds__(256) void gather_rel_kernel(
    const float* __restrict__ rel, const int* __restrict__ ef,
    unsigned short* __restrict__ lg)
{
    const int idx = blockIdx.x * 256 + threadIdx.x;
    if (idx >= NEDGES * DMODEL) return;
    const int e = idx >> 9;
    const int col = idx & 511;
    lg[idx] = f2b(rel[(size_t)ef[e] * DMODEL + col]);
}

__global__ __launch_bounds__(256) void cast_f2b_kernel(
    const float* __restrict__ in, unsigned short* __restrict__ out, int n)
{
    const int idx = blockIdx.x * 256 + threadIdx.x;
    if (idx < n) out[idx] = f2b(in[idx]);
}

__global__ __launch_bounds__(256) void cast_b2f_kernel(
    const unsigned short* __restrict__ in, float* __restrict__ out, int n)
{
    const int idx = blockIdx.x * 256 + threadIdx.x;
    if (idx < n) out[idx] = b2f(in[idx]);
}

__global__ __launch_bounds__(256) void zero_kernel(float4* __restrict__ p, int n4)
{
    const int idx = blockIdx.x * 256 + threadIdx.x;
    if (idx < n4) p[idx] = make_float4(0.f, 0.f, 0.f, 0.f);
}

// ---------------------------------------------------------------------------
static inline void mgemm(hipStream_t st, const unsigned short* A, const unsigned short* Bt,
                         const float* bias, const unsigned short* add, const int* gidx,
                         unsigned short* C, int M, int K, int N, int relu)
{
    GemmDst P = {C, nullptr, nullptr, add, nullptr, nullptr,
                 gidx, nullptr, nullptr, bias, nullptr, nullptr};
    dim3 g(N / BN, (M + BM - 1) / BM);
    mfma_gemm_kernel<<<g, 256, 0, st>>>(A, Bt, P, M, K, N, N, relu);
}

static inline void mgemm256(hipStream_t st, const unsigned short* A, const unsigned short* Bt,
                            const float* bias, const unsigned short* add, const int* gidx,
                            unsigned short* C, int M, int K, int N, int relu)
{
    GemmDst P = {C, nullptr, nullptr, add, nullptr, nullptr,
                 gidx, nullptr, nullptr, bias, nullptr, nullptr};
    dim3 g(N / TN, (M + TM - 1) / TM);
    mfma_gemm256_kernel<<<g, 512, 0, st>>>(A, Bt, P, M, K, N, N, relu);
}

static inline void mgemm_qkv(hipStream_t st, const unsigned short* A, const unsigned short* Bt,
                             const float* biasQ,
                             const unsigned short* addQ, const int* gxQ,
                             const unsigned short* addKV, const int* gxKV,
                             unsigned short* Cq, unsigned short* Ck, unsigned short* Cv,
                             int M, int K)
{
    GemmDst P = {Cq, Ck, Cv, addQ, addKV, addKV,
                 gxQ, gxKV, gxKV, biasQ, nullptr, nullptr};
    dim3 g(1536 / BN, (M + BM - 1) / BM);
    mfma_gemm_kernel<<<g, 256, 0, st>>>(A, Bt, P, M, K, 1536, 512, 0);
}

static inline void mgemm256_qkv(hipStream_t st, const unsigned short* A, const unsigned short* Bt,
                                const float* biasQ,
                                const unsigned short* addQ, const int* gxQ,
                                const unsigned short* addKV, const int* gxKV,
                                unsigned short* Cq, unsigned short* Ck, unsigned short* Cv,
                                int M, int K)
{
    GemmDst P = {Cq, Ck, Cv, addQ, addKV, addKV,
                 gxQ, gxKV, gxKV, biasQ, nullptr, nullptr};
    dim3 g(1536 / TN, (M + TM - 1) / TM);
    mfma_gemm256_kernel<<<g, 512, 0, st>>>(A, Bt, P, M, K, 1536, 512, 0);
}

static inline void tcast(hipStream_t st, const float* W, unsigned short* Wt, int K, int N)
{
    dim3 g(N / 32, K / 32);
    transpose_cast_kernel<<<g, 256, 0, st>>>(W, Wt, K, N);
}
static inline void zero(hipStream_t st, void* p, size_t nfloats)
{
    const int n4 = (int)(nfloats / 4);
    zero_kernel<<<(n4 + 255) / 256, 256, 0, st>>>((float4*)p, n4);
}

extern "C" void kernel_launch(void* const* d_in, const int* in_sizes, int n_in,
                              void* d_out, int out_size, void* d_ws, size_t ws_size,
                              hipStream_t stream)
{
    const float* x_in      = (const float*)d_in[0];
    const int*   edge_feat = (const int*)d_in[1];
    const int*   src_ids   = (const int*)d_in[2];
    const int*   dst_ids   = (const int*)d_in[3];
    const int*   lg_src    = (const int*)d_in[4];
    const int*   lg_dst    = (const int*)d_in[5];
    const float* rel_embed = (const float*)d_in[6];

    const float* n_Wq = (const float*)d_in[7];   const float* n_bq = (const float*)d_in[8];
    const float* n_Wk = (const float*)d_in[9];   const float* n_Wv = (const float*)d_in[10];
    const float* n_Wo = (const float*)d_in[11];  const float* n_bo = (const float*)d_in[12];
    const float* n_lg = (const float*)d_in[13];  const float* n_lb = (const float*)d_in[14];
    const float* n_f1 = (const float*)d_in[15];  const float* n_fb1 = (const float*)d_in[16];
    const float* n_f2 = (const float*)d_in[17];  const float* n_fb2 = (const float*)d_in[18];
    const float* n_fg = (const float*)d_in[19];  const float* n_fb = (const float*)d_in[20];

    const float* e_Wq = (const float*)d_in[21];  const float* e_bq = (const float*)d_in[22];
    const float* e_Wk = (const float*)d_in[23];  const float* e_Wv = (const float*)d_in[24];
    const float* e_Wo = (const float*)d_in[25];  const float* e_bo = (const float*)d_in[26];
    const float* e_lg = (const float*)d_in[27];  const float* e_lb = (const float*)d_in[28];
    const float* e_f1 = (const float*)d_in[29];  const float* e_fb1 = (const float*)d_in[30];
    const float* e_f2 = (const float*)d_in[31];  const float* e_fb2 = (const float*)d_in[32];
    const float* e_fg = (const float*)d_in[33];  const float* e_fb = (const float*)d_in[34];

    const int XSZ  = NNODES * DMODEL;
    const int LGSZ = NEDGES * DMODEL;

    // ---- workspace layout ---------------------------------------------------
    char* ws = (char*)d_ws;
    unsigned short* lg16  = (unsigned short*)(ws);               // 51,200,000 B
    unsigned short* ve16  = (unsigned short*)(ws + 51200000);    // 51,200,000 B
    int* n_off = (int*)(ws + 102400000);
    int* n_cur = (int*)(ws + 102420480);
    int* n_idx = (int*)(ws + 102440960);
    int* e_off = (int*)(ws + 102641664);
    int* e_cur = (int*)(ws + 102842368);
    int* e_idx = (int*)(ws + 103043072);                         // ends 103.84 MB
    unsigned short* xbufA = (unsigned short*)(ws + 110400000);   // 5,120,000 B
    unsigned short* xbufB = (unsigned short*)(ws + 115520000);   // 5,120,000 B

    // ---- d_out scratch (112.64 MB) -----------------------------------------
    char* ob = (char*)d_out;
    unsigned short* qe16 = (unsigned short*)(ob);                // 51.2 MB
    unsigned short* ke16 = (unsigned short*)(ob + 51200000);     // 51.2 MB
    unsigned short* ehid = (unsigned short*)(ob);                // 102.4 MB (edge FFN hidden; qe/ke dead then)
    unsigned short* nq16 = (unsigned short*)(ob);
    unsigned short* nk16 = (unsigned short*)(ob + 5120000);
    unsigned short* nv16 = (unsigned short*)(ob + 10240000);
    unsigned short* nhid = (unsigned short*)(ob);                // 20.48 MB
    unsigned short* wtq  = (unsigned short*)(ob + 102400000);    // q|k|v contiguous
    unsigned short* wtk  = (unsigned short*)(ob + 102924288);
    unsigned short* wtv  = (unsigned short*)(ob + 103448576);
    unsigned short* wto  = (unsigned short*)(ob + 103972864);
    unsigned short* wtf1 = (unsigned short*)(ob + 104497152);    // 2 MB
    unsigned short* wtf2 = (unsigned short*)(ob + 106594304);    // 2 MB (ends 108.7 MB)

    // ---- init + CSR build ---------------------------------------------------
    cast_f2b_kernel<<<(XSZ + 255) / 256, 256, 0, stream>>>(x_in, xbufA, XSZ);
    gather_rel_kernel<<<(LGSZ + 255) / 256, 256, 0, stream>>>(rel_embed, edge_feat, lg16);

    zero(stream, n_cur, NNODES);
    zero(stream, e_cur, NEDGES);
    hist_kernel<<<(NEDGES + 255) / 256, 256, 0, stream>>>(dst_ids, n_cur, NEDGES);
    hist_kernel<<<(NELG + 255) / 256, 256, 0, stream>>>(lg_dst, e_cur, NELG);
    scan_kernel<<<1, 1024, 0, stream>>>(n_cur, n_off, n_cur, NNODES);
    scan_kernel<<<1, 1024, 0, stream>>>(e_cur, e_off, e_cur, NEDGES);
    scatter_kernel<<<(NEDGES + 255) / 256, 256, 0, stream>>>(dst_ids, n_cur, n_idx, NEDGES);
    scatter_kernel<<<(NELG + 255) / 256, 256, 0, stream>>>(lg_dst, e_cur, e_idx, NELG);

    unsigned short* xc = xbufA;
    unsigned short* xn = xbufB;

    for (int i = 0; i < NLAYERS; ++i) {
        const size_t wo  = (size_t)i * DMODEL * DMODEL;
        const size_t bo_ = (size_t)i * DMODEL;
        const size_t f1o = (size_t)i * DMODEL * 4 * DMODEL;
        const size_t b1o = (size_t)i * 4 * DMODEL;
        const size_t f2o = (size_t)i * 4 * DMODEL * DMODEL;

        // ================= node update (reads xc, lg16) =================
        tcast(stream, n_Wq + wo, wtq, 512, 512);
        tcast(stream, n_Wk + wo, wtk, 512, 512);
        tcast(stream, n_Wv + wo, wtv, 512, 512);
        tcast(stream, n_Wo + wo, wto, 512, 512);
        tcast(stream, n_f1 + f1o, wtf1, 512, 2048);
        tcast(stream, n_f2 + f2o, wtf2, 2048, 512);

        mgemm_qkv(stream, xc, wtq, n_bq + bo_,
                  nullptr, nullptr, nullptr, nullptr,
                  nq16, nk16, nv16, NNODES, 512);

        attend_kernel<<<(NNODES + 3) / 4, 256, 0, stream>>>(
            nq16, nk16, nv16, lg16, src_ids, n_off, n_idx, NNODES);

        mgemm(stream, nq16, wto, n_bo + bo_, xc, nullptr, xn, NNODES, 512, 512, 0);
        ln_kernel<<<(NNODES + 3) / 4, 256, 0, stream>>>(xn, n_lg + bo_, n_lb + bo_, NNODES);
        mgemm(stream, xn, wtf1, n_fb1 + b1o, nullptr, nullptr, nhid, NNODES, 512, 2048, 1);
        mgemm(stream, nhid, wtf2, n_fb2 + bo_, xn, nullptr, xn, NNODES, 2048, 512, 0);
        ln_kernel<<<(NNODES + 3) / 4, 256, 0, stream>>>(xn, n_fg + bo_, n_fb + bo_, NNODES);

        // ================= edge update (reads PRE-update xc) =================
        tcast(stream, e_Wq + wo, wtq, 512, 512);
        tcast(stream, e_Wk + wo, wtk, 512, 512);
        tcast(stream, e_Wv + wo, wtv, 512, 512);
        tcast(stream, e_Wo + wo, wto, 512, 512);

        mgemm256_qkv(stream, lg16, wtq, e_bq + bo_,
                     xc, dst_ids, xc, src_ids,
                     qe16, ke16, ve16, NEDGES, 512);

        attend_kernel<<<(NEDGES + 3) / 4, 256, 0, stream>>>(
            qe16, ke16, ve16, nullptr, lg_src, e_off, e_idx, NEDGES);

        mgemm(stream, qe16, wto, e_bo + bo_, lg16, nullptr, lg16, NEDGES, 512, 512, 0);
        ln_kernel<<<(NEDGES + 3) / 4, 256, 0, stream>>>(lg16, e_lg + bo_, e_lb + bo_, NEDGES);

        // qe16/ke16 dead now -> 102.4 MB hidden buffer, 2 chunks of 25000
        tcast(stream, e_f1 + f1o, wtf1, 512, 2048);
        tcast(stream, e_f2 + f2o, wtf2, 2048, 512);
        for (int c = 0; c < 2; ++c) {
            unsigned short* y1c = lg16 + (size_t)c * 25000 * DMODEL;
            mgemm256(stream, y1c, wtf1, e_fb1 + b1o, nullptr, nullptr, ehid, 25000, 512, 2048, 1);
            mgemm(stream, ehid, wtf2, e_fb2 + bo_, y1c, nullptr, y1c, 25000, 2048, 512, 0);
        }
        ln_kernel<<<(NEDGES + 3) / 4, 256, 0, stream>>>(lg16, e_fg + bo_, e_fb + bo_, NEDGES);

        unsigned short* t = xc; xc = xn; xn = t;
    }

    // final: bf16 -> fp32 d_out (all d_out scratch dead now)
    float* out_f = (float*)d_out;
    cast_b2f_kernel<<<(XSZ + 255) / 256, 256, 0, stream>>>(xc, out_f, XSZ);
    cast_b2f_kernel<<<(LGSZ + 255) / 256, 256, 0, stream>>>(lg16, out_f + XSZ, LGSZ);
}

// Round 9
// 2242.480 us; speedup vs baseline: 1.0890x; 1.0073x over previous
//
#include <hip/hip_runtime.h>
#include <math.h>

#define NNODES 5000
#define NEDGES 50000
#define NELG   200000
#define DMODEL 512
#define NH     8
#define NLAYERS 2

typedef __bf16 bf16x8 __attribute__((ext_vector_type(8)));
typedef float  f32x4  __attribute__((ext_vector_type(4)));
typedef unsigned short us8v __attribute__((ext_vector_type(8)));
typedef unsigned short us4v __attribute__((ext_vector_type(4)));

// ---- bf16 helpers (stored as unsigned short) ------------------------------
__device__ __forceinline__ float b2f(unsigned short u) {
    union { unsigned int i; float f; } c;
    c.i = ((unsigned int)u) << 16;
    return c.f;
}
__device__ __forceinline__ unsigned short f2b(float f) {
    union { float f; unsigned int i; } c;
    c.f = f;
    unsigned int i = c.i;
    return (unsigned short)((i + 0x7fffu + ((i >> 16) & 1u)) >> 16);
}

struct GemmDst {
    unsigned short* C0; unsigned short* C1; unsigned short* C2;
    const unsigned short* a0; const unsigned short* a1; const unsigned short* a2;
    const int* x0; const int* x1; const int* x2;
    const float* b0; const float* b1; const float* b2;
};

// ---------------------------------------------------------------------------
// 128^2 GEMM (round-3, proven): BK=32, 16 KB LDS, __syncthreads, XCD panel
// swizzle, swapped-operand MFMA -> vectorized D^T epilogue. 8 blocks/CU.
// ---------------------------------------------------------------------------
#define BM 128
#define BN 128
#define BK 32

__global__ __launch_bounds__(256) void mfma_gemm_kernel(
    const unsigned short* __restrict__ A, const unsigned short* __restrict__ Bt,
    GemmDst P, int M, int K, int N, int secN, int relu)
{
    __shared__ __align__(16) unsigned short ldsA[BM * BK];  // 8 KB
    __shared__ __align__(16) unsigned short ldsB[BN * BK];  // 8 KB

    // ---- panel-to-XCD swizzle (bijective remap, dispatch wgid%8 = XCD) ----
    const int nbx  = gridDim.x;
    const int nb   = nbx * gridDim.y;
    const int wgid = blockIdx.y * nbx + blockIdx.x;
    const int xcd  = wgid & 7;
    const int ii   = wgid >> 3;
    const int q8   = nb >> 3, r8 = nb & 7;
    const int base = (xcd < r8) ? xcd * (q8 + 1) : r8 * (q8 + 1) + (xcd - r8) * q8;
    const int tl   = base + ii;
    const int rowBase = (tl / nbx) * BM;
    const int colBase = (tl % nbx) * BN;

    const int tid  = threadIdx.x;
    const int lane = tid & 63;
    const int wave = tid >> 6;
    const int quad = lane >> 4;
    const int l16  = lane & 15;
    const int wm = (wave >> 1) * 64;
    const int wn = (wave & 1) * 64;

    const int g0 = tid, g1 = tid + 256;
    const int r0 = g0 >> 2, r1 = g1 >> 2;
    const int c0g = (g0 & 3) ^ ((r0 >> 1) & 3);
    const int c1g = (g1 & 3) ^ ((r1 >> 1) & 3);
    int ra0 = rowBase + r0; if (ra0 > M - 1) ra0 = M - 1;
    int ra1 = rowBase + r1; if (ra1 > M - 1) ra1 = M - 1;
    const unsigned short* gA0 = A + (size_t)ra0 * K + c0g * 8;
    const unsigned short* gA1 = A + (size_t)ra1 * K + c1g * 8;
    const unsigned short* gB0 = Bt + (size_t)(colBase + r0) * K + c0g * 8;
    const unsigned short* gB1 = Bt + (size_t)(colBase + r1) * K + c1g * 8;
    unsigned short* lA0 = ldsA + g0 * 8;
    unsigned short* lA1 = ldsA + g1 * 8;
    unsigned short* lB0 = ldsB + g0 * 8;
    unsigned short* lB1 = ldsB + g1 * 8;

    const int swz = (l16 >> 1) & 3;
    const int ca = (quad ^ swz) * 8;

    const f32x4 zv = {0.f, 0.f, 0.f, 0.f};
    f32x4 acc[4][4];
    #pragma unroll
    for (int i = 0; i < 4; ++i)
        #pragma unroll
        for (int j = 0; j < 4; ++j) acc[i][j] = zv;

    for (int k0 = 0; k0 < K; k0 += BK) {
        __builtin_amdgcn_global_load_lds(
            (const __attribute__((address_space(1))) void*)(gA0 + k0),
            (__attribute__((address_space(3))) void*)lA0, 16, 0, 0);
        __builtin_amdgcn_global_load_lds(
            (const __attribute__((address_space(1))) void*)(gA1 + k0),
            (__attribute__((address_space(3))) void*)lA1, 16, 0, 0);
        __builtin_amdgcn_global_load_lds(
            (const __attribute__((address_space(1))) void*)(gB0 + k0),
            (__attribute__((address_space(3))) void*)lB0, 16, 0, 0);
        __builtin_amdgcn_global_load_lds(
            (const __attribute__((address_space(1))) void*)(gB1 + k0),
            (__attribute__((address_space(3))) void*)lB1, 16, 0, 0);
        __syncthreads();

        bf16x8 af[4], bfr[4];
        #pragma unroll
        for (int i = 0; i < 4; ++i)
            af[i] = *(const bf16x8*)(ldsA + (wm + i * 16 + l16) * BK + ca);
        #pragma unroll
        for (int j = 0; j < 4; ++j)
            bfr[j] = *(const bf16x8*)(ldsB + (wn + j * 16 + l16) * BK + ca);
        #pragma unroll
        for (int i = 0; i < 4; ++i)
            #pragma unroll
            for (int j = 0; j < 4; ++j)
                acc[i][j] = __builtin_amdgcn_mfma_f32_16x16x32_bf16(
                    bfr[j], af[i], acc[i][j], 0, 0, 0);
        __syncthreads();
    }

    const int sec   = colBase / secN;
    const int cbase = colBase - sec * secN;
    unsigned short*       Cs = (sec == 0) ? P.C0 : ((sec == 1) ? P.C1 : P.C2);
    const unsigned short* ad = (sec == 0) ? P.a0 : ((sec == 1) ? P.a1 : P.a2);
    const int*            gx = (sec == 0) ? P.x0 : ((sec == 1) ? P.x1 : P.x2);
    const float*          bs = (sec == 0) ? P.b0 : ((sec == 1) ? P.b1 : P.b2);

    f32x4 b4[4];
    #pragma unroll
    for (int j = 0; j < 4; ++j) {
        const int n0 = cbase + wn + j * 16 + quad * 4;
        b4[j] = bs ? *(const f32x4*)(bs + n0) : zv;
    }

    #pragma unroll
    for (int i = 0; i < 4; ++i) {
        const int row = rowBase + wm + i * 16 + l16;
        if (row >= M) continue;
        const int arow = gx ? gx[row] : row;
        const unsigned short* ar = ad ? ad + (size_t)arow * secN : nullptr;
        unsigned short* crow = Cs + (size_t)row * secN;
        #pragma unroll
        for (int j = 0; j < 4; ++j) {
            const int n0 = cbase + wn + j * 16 + quad * 4;
            f32x4 v = acc[i][j];
            v += b4[j];
            if (ar) {
                const us4v r4 = *(const us4v*)(ar + n0);
                #pragma unroll
                for (int r = 0; r < 4; ++r) v[r] += b2f(r4[r]);
            }
            if (relu) {
                #pragma unroll
                for (int r = 0; r < 4; ++r) v[r] = fmaxf(v[r], 0.0f);
            }
            us4v o4;
            #pragma unroll
            for (int r = 0; r < 4; ++r) o4[r] = f2b(v[r]);
            *(us4v*)(crow + n0) = o4;
        }
    }
}

// ---------------------------------------------------------------------------
// 256^2 GEMM (round-8, best measured). 4-phase schedule + counted sync.
// Plateau ~485 TF is a per-CU staging-latency/queue limit — do not iterate
// the K-loop sync further (rounds 4/6/8 tie within 2.5%).
// ---------------------------------------------------------------------------
#define TM 256
#define TN 256
#define TK 64

__global__ __launch_bounds__(512, 1) void mfma_gemm256_kernel(
    const unsigned short* __restrict__ A, const unsigned short* __restrict__ Bt,
    GemmDst P, int M, int K, int N, int secN, int relu)
{
    __shared__ __align__(16) unsigned short ldsA[2][TM * TK];  // 2 x 32 KB
    __shared__ __align__(16) unsigned short ldsB[2][TN * TK];  // 2 x 32 KB

    // ---- panel-to-XCD swizzle ----
    const int nbx  = gridDim.x;
    const int nb   = nbx * gridDim.y;
    const int wgid = blockIdx.y * nbx + blockIdx.x;
    const int xcd  = wgid & 7;
    const int ii   = wgid >> 3;
    const int q8   = nb >> 3, r8 = nb & 7;
    const int base = (xcd < r8) ? xcd * (q8 + 1) : r8 * (q8 + 1) + (xcd - r8) * q8;
    const int tl   = base + ii;
    const int rowBase = (tl / nbx) * TM;
    const int colBase = (tl % nbx) * TN;

    const int tid  = threadIdx.x;           // 0..511
    const int lane = tid & 63;
    const int wave = tid >> 6;               // 0..7
    const int quad = lane >> 4;
    const int l16  = lane & 15;
    const int wr   = wave >> 2;              // 0..1 (M)
    const int wc   = wave & 3;               // 0..3 (N)

    const unsigned short* srcA[4];
    const unsigned short* srcB[4];
    int ldsOff[4];
    #pragma unroll
    for (int j = 0; j < 4; ++j) {
        const int p = j * 512 + tid;
        const int r = p >> 3;
        const int c = (p & 7) ^ (r & 7);
        ldsOff[j] = p * 8;
        int rA = rowBase + r; if (rA > M - 1) rA = M - 1;
        srcA[j] = A + (size_t)rA * K + c * 8;
        srcB[j] = Bt + (size_t)(colBase + r) * K + c * 8;
    }

    const int ca0 = (quad       ^ (l16 & 7)) * 8;
    const int ca1 = ((quad + 4) ^ (l16 & 7)) * 8;
    const int aRow0 = wr * 128 + l16;
    const int bRow0 = wc * 64 + l16;

    const f32x4 zv = {0.f, 0.f, 0.f, 0.f};
    f32x4 acc[8][4];
    #pragma unroll
    for (int i = 0; i < 8; ++i)
        #pragma unroll
        for (int j = 0; j < 4; ++j) acc[i][j] = zv;

#define STG2(dst, src, kn, j0)                                                \
    {                                                                         \
        _Pragma("unroll")                                                     \
        for (int j = (j0); j < (j0) + 2; ++j)                                 \
            __builtin_amdgcn_global_load_lds(                                 \
                (const __attribute__((address_space(1))) void*)((src)[j] + (kn)), \
                (__attribute__((address_space(3))) void*)((dst) + ldsOff[j]), \
                16, 0, 0);                                                    \
    }

#define PHASE(CS, MBASE, READB, STG)                                          \
    {                                                                         \
        _Pragma("unroll")                                                     \
        for (int m = 0; m < 4; ++m)                                           \
            afr[m] = *(const bf16x8*)(bA + (aRow0 + ((MBASE) + m) * 16) * TK + (CS)); \
        if (READB) {                                                          \
            _Pragma("unroll")                                                 \
            for (int n = 0; n < 4; ++n)                                       \
                bfr[n] = *(const bf16x8*)(bB + (bRow0 + n * 16) * TK + (CS)); \
        }                                                                     \
        STG;                                                                  \
        __builtin_amdgcn_s_barrier();                                         \
        __builtin_amdgcn_sched_barrier(0);                                    \
        __builtin_amdgcn_s_setprio(1);                                        \
        _Pragma("unroll")                                                     \
        for (int m = 0; m < 4; ++m)                                           \
            _Pragma("unroll")                                                 \
            for (int n = 0; n < 4; ++n)                                       \
                acc[(MBASE) + m][n] = __builtin_amdgcn_mfma_f32_16x16x32_bf16(\
                    bfr[n], afr[m], acc[(MBASE) + m][n], 0, 0, 0);            \
        __builtin_amdgcn_s_setprio(0);                                        \
        __builtin_amdgcn_sched_barrier(0);                                    \
    }

    const int nt = K / TK;

    STG2(ldsA[0], srcA, 0, 0); STG2(ldsA[0], srcA, 0, 2);
    STG2(ldsB[0], srcB, 0, 0); STG2(ldsB[0], srcB, 0, 2);
    asm volatile("s_waitcnt vmcnt(0)" ::: "memory");
    __builtin_amdgcn_s_barrier();
    __builtin_amdgcn_sched_barrier(0);

    for (int t = 0; t < nt; ++t) {
        const int cur = t & 1;
        const unsigned short* bA = ldsA[cur];
        const unsigned short* bB = ldsB[cur];
        unsigned short* dA = ldsA[cur ^ 1];
        unsigned short* dB = ldsB[cur ^ 1];
        const bool pf = (t + 1 < nt);
        const int kn = (t + 1) * TK;
        bf16x8 afr[4], bfr[4];

        PHASE(ca0, 0, 1, if (pf) STG2(dA, srcA, kn, 0));
        __builtin_amdgcn_s_barrier();
        PHASE(ca0, 4, 0, if (pf) STG2(dA, srcA, kn, 2));
        __builtin_amdgcn_s_barrier();
        PHASE(ca1, 0, 1, if (pf) STG2(dB, srcB, kn, 0));
        __builtin_amdgcn_s_barrier();
        PHASE(ca1, 4, 0, if (pf) STG2(dB, srcB, kn, 2));
        if (pf) asm volatile("s_waitcnt vmcnt(0)" ::: "memory");
        __builtin_amdgcn_s_barrier();
        __builtin_amdgcn_sched_barrier(0);
    }

#undef PHASE
#undef STG2

    const int sec   = colBase / secN;
    const int cbase = colBase - sec * secN;
    unsigned short*       Cs = (sec == 0) ? P.C0 : ((sec == 1) ? P.C1 : P.C2);
    const unsigned short* ad = (sec == 0) ? P.a0 : ((sec == 1) ? P.a1 : P.a2);
    const int*            gx = (sec == 0) ? P.x0 : ((sec == 1) ? P.x1 : P.x2);
    const float*          bs = (sec == 0) ? P.b0 : ((sec == 1) ? P.b1 : P.b2);

    f32x4 b4[4];
    #pragma unroll
    for (int n = 0; n < 4; ++n) {
        const int n0 = cbase + wc * 64 + n * 16 + quad * 4;
        b4[n] = bs ? *(const f32x4*)(bs + n0) : zv;
    }

    #pragma unroll
    for (int m = 0; m < 8; ++m) {
        const int row = rowBase + wr * 128 + m * 16 + l16;
        if (row >= M) continue;
        const int arow = gx ? gx[row] : row;
        const unsigned short* ar = ad ? ad + (size_t)arow * secN : nullptr;
        unsigned short* crow = Cs + (size_t)row * secN;
        #pragma unroll
        for (int n = 0; n < 4; ++n) {
            const int n0 = cbase + wc * 64 + n * 16 + quad * 4;
            f32x4 v = acc[m][n];
            v += b4[n];
            if (ar) {
                const us4v r4 = *(const us4v*)(ar + n0);
                #pragma unroll
                for (int r = 0; r < 4; ++r) v[r] += b2f(r4[r]);
            }
            if (relu) {
                #pragma unroll
                for (int r = 0; r < 4; ++r) v[r] = fmaxf(v[r], 0.0f);
            }
            us4v o4;
            #pragma unroll
            for (int r = 0; r < 4; ++r) o4[r] = f2b(v[r]);
            *(us4v*)(crow + n0) = o4;
        }
    }
}

// ---------------------------------------------------------------------------
// Batched W[K][N] fp32 -> Wt[N][K] bf16: up to 6 weights per launch (cuts
// 12 tcast launches/layer to 2). Flat grid; per-desc block-range offsets.
// ---------------------------------------------------------------------------
struct TcB {
    const float* W[6];
    unsigned short* Wt[6];
    int K[6]; int N[6]; int off[7]; int cnt;
};

__global__ __launch_bounds__(256) void tcast_batch_kernel(TcB B)
{
    __shared__ float t[32][33];
    const int bid = blockIdx.x;
    int d = 0;
    #pragma unroll
    for (int i = 1; i < 6; ++i)
        if (i < B.cnt && bid >= B.off[i]) d = i;
    const int lb  = bid - B.off[d];
    const int nbx = B.N[d] >> 5;
    const int bx = lb % nbx, by = lb / nbx;
    const float* W = B.W[d];
    unsigned short* Wt = B.Wt[d];
    const int K = B.K[d], N = B.N[d];
    const int n0 = bx << 5, k0 = by << 5;
    const int tx = threadIdx.x & 31, ty = threadIdx.x >> 5;
    #pragma unroll
    for (int r = 0; r < 32; r += 8)
        t[ty + r][tx] = W[(size_t)(k0 + ty + r) * N + n0 + tx];
    __syncthreads();
    #pragma unroll
    for (int r = 0; r < 32; r += 8)
        Wt[(size_t)(n0 + ty + r) * K + k0 + tx] = f2b(t[tx][ty + r]);
}

// ---------------------------------------------------------------------------
// LayerNorm over bf16 rows of width 512. One wave per row. If o32 != null,
// writes fp32 rows to o32 (final-layer fusion) instead of in-place bf16.
// ---------------------------------------------------------------------------
__global__ __launch_bounds__(256) void ln_kernel(
    unsigned short* __restrict__ x, const float* __restrict__ g,
    const float* __restrict__ b, int M, float* __restrict__ o32)
{
    const int row = blockIdx.x * 4 + (threadIdx.x >> 6);
    if (row >= M) return;
    const int lane = threadIdx.x & 63;
    unsigned short* xr = x + (size_t)row * DMODEL;

    float vals[8];
    float s = 0.f, s2 = 0.f;
    #pragma unroll
    for (int i = 0; i < 8; ++i) {
        const float v = b2f(xr[lane + i * 64]);
        vals[i] = v; s += v; s2 += v * v;
    }
    #pragma unroll
    for (int o = 32; o > 0; o >>= 1) {
        s  += __shfl_down(s, o);
        s2 += __shfl_down(s2, o);
    }
    s  = __shfl(s, 0);
    s2 = __shfl(s2, 0);
    const float m = s * (1.0f / DMODEL);
    const float var = s2 * (1.0f / DMODEL) - m * m;
    const float r = rsqrtf(var + 1e-5f);
    if (o32) {
        float* orow = o32 + (size_t)row * DMODEL;
        #pragma unroll
        for (int i = 0; i < 8; ++i) {
            const int c = lane + i * 64;
            orow[c] = (vals[i] - m) * r * g[c] + b[c];
        }
    } else {
        #pragma unroll
        for (int i = 0; i < 8; ++i) {
            const int c = lane + i * 64;
            xr[c] = f2b((vals[i] - m) * r * g[c] + b[c]);
        }
    }
}

// ---------------------------------------------------------------------------
// CSR build: histogram -> single-block scan -> scatter
// ---------------------------------------------------------------------------
__global__ __launch_bounds__(256) void hist_kernel(
    const int* __restrict__ dst, int* __restrict__ cnt, int ne)
{
    const int j = blockIdx.x * 256 + threadIdx.x;
    if (j < ne) atomicAdd(&cnt[dst[j]], 1);
}

__global__ __launch_bounds__(1024) void scan_kernel(
    const int* __restrict__ cnt, int* __restrict__ off,
    int* __restrict__ cur, int n)
{
    __shared__ int part[1024];
    const int t = threadIdx.x;
    const int chunk = (n + 1023) >> 10;
    const int lo = t * chunk;
    int hi = lo + chunk; if (hi > n) hi = n;
    int s = 0;
    for (int i = lo; i < hi; ++i) s += cnt[i];
    part[t] = s;
    __syncthreads();
    #pragma unroll
    for (int o = 1; o < 1024; o <<= 1) {
        int v = (t >= o) ? part[t - o] : 0;
        __syncthreads();
        part[t] += v;
        __syncthreads();
    }
    int base = (t == 0) ? 0 : part[t - 1];
    const int total = part[1023];
    for (int i = lo; i < hi; ++i) {
        const int c = cnt[i];
        off[i] = base; cur[i] = base;
        base += c;
    }
    if (t == 1023) off[n] = total;
}

__global__ __launch_bounds__(256) void scatter_kernel(
    const int* __restrict__ dst, int* __restrict__ cur,
    int* __restrict__ idx, int ne)
{
    const int j = blockIdx.x * 256 + threadIdx.x;
    if (j < ne) {
        const int p = atomicAdd(&cur[dst[j]], 1);
        idx[p] = j;
    }
}

// ---------------------------------------------------------------------------
// Fused CSR attention: ONE WAVE per destination segment (4 segs/block).
// 2-way edge unroll: the per-edge idx->src->k/v gather chain is 3 dependent
// loads (~200-900 cyc each) with a runtime trip count the compiler won't
// pipeline; two concurrent chains halve exposed latency.
// ---------------------------------------------------------------------------
__global__ __launch_bounds__(256) void attend_kernel(
    unsigned short* __restrict__ q,
    const unsigned short* __restrict__ k,
    const unsigned short* __restrict__ v,
    const unsigned short* __restrict__ efeat,
    const int* __restrict__ src,
    const int* __restrict__ off, const int* __restrict__ idx,
    int nseg)
{
    const int wave = threadIdx.x >> 6, lane = threadIdx.x & 63;
    const int seg = blockIdx.x * 4 + wave;
    if (seg >= nseg) return;
    const int c8 = lane * 8;
    unsigned short* qrow = q + (size_t)seg * DMODEL;

    const us8v q8 = *(const us8v*)(qrow + c8);
    float qv[8];
    #pragma unroll
    for (int j = 0; j < 8; ++j) qv[j] = b2f(q8[j]);

    float acc[8] = {0.f, 0.f, 0.f, 0.f, 0.f, 0.f, 0.f, 0.f};
    float zsum = 0.f;
    const int lo = off[seg], hi = off[seg + 1];

    int jj = lo;
    for (; jj + 2 <= hi; jj += 2) {
        const int e0 = idx[jj];
        const int e1 = idx[jj + 1];
        const int s0 = src[e0];
        const int s1 = src[e1];
        const us8v k80 = *(const us8v*)(k + (size_t)s0 * DMODEL + c8);
        const us8v v80 = *(const us8v*)(v + (size_t)s0 * DMODEL + c8);
        const us8v k81 = *(const us8v*)(k + (size_t)s1 * DMODEL + c8);
        const us8v v81 = *(const us8v*)(v + (size_t)s1 * DMODEL + c8);
        float p0 = 0.f, p1 = 0.f;
        float vv0[8], vv1[8];
        if (efeat) {
            const us8v e80 = *(const us8v*)(efeat + (size_t)e0 * DMODEL + c8);
            const us8v e81 = *(const us8v*)(efeat + (size_t)e1 * DMODEL + c8);
            #pragma unroll
            for (int j = 0; j < 8; ++j) {
                const float ef0 = b2f(e80[j]);
                const float ef1 = b2f(e81[j]);
                p0 = fmaf(b2f(k80[j]) + ef0, qv[j], p0);
                p1 = fmaf(b2f(k81[j]) + ef1, qv[j], p1);
                vv0[j] = b2f(v80[j]) + ef0;
                vv1[j] = b2f(v81[j]) + ef1;
            }
        } else {
            #pragma unroll
            for (int j = 0; j < 8; ++j) {
                p0 = fmaf(b2f(k80[j]), qv[j], p0);
                p1 = fmaf(b2f(k81[j]), qv[j], p1);
                vv0[j] = b2f(v80[j]);
                vv1[j] = b2f(v81[j]);
            }
        }
        p0 += __shfl_xor(p0, 1); p1 += __shfl_xor(p1, 1);
        p0 += __shfl_xor(p0, 2); p1 += __shfl_xor(p1, 2);
        p0 += __shfl_xor(p0, 4); p1 += __shfl_xor(p1, 4);
        float sc0 = fminf(fmaxf(p0 * 0.125f, -10.0f), 10.0f);
        float sc1 = fminf(fmaxf(p1 * 0.125f, -10.0f), 10.0f);
        sc0 = __expf(sc0);
        sc1 = __expf(sc1);
        zsum += sc0 + sc1;
        #pragma unroll
        for (int j = 0; j < 8; ++j) {
            acc[j] = fmaf(sc0, vv0[j], acc[j]);
            acc[j] = fmaf(sc1, vv1[j], acc[j]);
        }
    }
    if (jj < hi) {
        const int e = idx[jj];
        const int s = src[e];
        const us8v k8 = *(const us8v*)(k + (size_t)s * DMODEL + c8);
        const us8v v8 = *(const us8v*)(v + (size_t)s * DMODEL + c8);
        float p = 0.f;
        float vv[8];
        if (efeat) {
            const us8v e8 = *(const us8v*)(efeat + (size_t)e * DMODEL + c8);
            #pragma unroll
            for (int j = 0; j < 8; ++j) {
                const float ef = b2f(e8[j]);
                p = fmaf(b2f(k8[j]) + ef, qv[j], p);
                vv[j] = b2f(v8[j]) + ef;
            }
        } else {
            #pragma unroll
            for (int j = 0; j < 8; ++j) {
                p = fmaf(b2f(k8[j]), qv[j], p);
                vv[j] = b2f(v8[j]);
            }
        }
        p += __shfl_xor(p, 1);
        p += __shfl_xor(p, 2);
        p += __shfl_xor(p, 4);
        float sc = fminf(fmaxf(p * 0.125f, -10.0f), 10.0f);
        sc = __expf(sc);
        zsum += sc;
        #pragma unroll
        for (int j = 0; j < 8; ++j) acc[j] = fmaf(sc, vv[j], acc[j]);
    }

    const float rz = 1.0f / zsum;
    us8v o8;
    #pragma unroll
    for (int j = 0; j < 8; ++j) o8[j] = f2b(acc[j] * rz);
    *(us8v*)(qrow + c8) = o8;
}

// ---------------------------------------------------------------------------
__global__ __launch_bounds__(256) void gather_rel_kernel(
    const float* __restrict__ rel, const int* __restrict__ ef,
    unsigned short* __restrict__ lg)
{
    const int idx = blockIdx.x * 256 + threadIdx.x;
    if (idx >= NEDGES * DMODEL) return;
    const int e = idx >> 9;
    const int col = idx & 511;
    lg[idx] = f2b(rel[(size_t)ef[e] * DMODEL + col]);
}

__global__ __launch_bounds__(256) void cast_f2b_kernel(
    const float* __restrict__ in, unsigned short* __restrict__ out, int n)
{
    const int idx = blockIdx.x * 256 + threadIdx.x;
    if (idx < n) out[idx] = f2b(in[idx]);
}

__global__ __launch_bounds__(256) void cast_b2f_kernel(
    const unsigned short* __restrict__ in, float* __restrict__ out, int n)
{
    const int idx = blockIdx.x * 256 + threadIdx.x;
    if (idx < n) out[idx] = b2f(in[idx]);
}

__global__ __launch_bounds__(256) void zero_kernel(float4* __restrict__ p, int n4)
{
    const int idx = blockIdx.x * 256 + threadIdx.x;
    if (idx < n4) p[idx] = make_float4(0.f, 0.f, 0.f, 0.f);
}

// ---------------------------------------------------------------------------
static inline void mgemm(hipStream_t st, const unsigned short* A, const unsigned short* Bt,
                         const float* bias, const unsigned short* add, const int* gidx,
                         unsigned short* C, int M, int K, int N, int relu)
{
    GemmDst P = {C, nullptr, nullptr, add, nullptr, nullptr,
                 gidx, nullptr, nullptr, bias, nullptr, nullptr};
    dim3 g(N / BN, (M + BM - 1) / BM);
    mfma_gemm_kernel<<<g, 256, 0, st>>>(A, Bt, P, M, K, N, N, relu);
}

static inline void mgemm256(hipStream_t st, const unsigned short* A, const unsigned short* Bt,
                            const float* bias, const unsigned short* add, const int* gidx,
                            unsigned short* C, int M, int K, int N, int relu)
{
    GemmDst P = {C, nullptr, nullptr, add, nullptr, nullptr,
                 gidx, nullptr, nullptr, bias, nullptr, nullptr};
    dim3 g(N / TN, (M + TM - 1) / TM);
    mfma_gemm256_kernel<<<g, 512, 0, st>>>(A, Bt, P, M, K, N, N, relu);
}

static inline void mgemm_qkv(hipStream_t st, const unsigned short* A, const unsigned short* Bt,
                             const float* biasQ,
                             const unsigned short* addQ, const int* gxQ,
                             const unsigned short* addKV, const int* gxKV,
                             unsigned short* Cq, unsigned short* Ck, unsigned short* Cv,
                             int M, int K)
{
    GemmDst P = {Cq, Ck, Cv, addQ, addKV, addKV,
                 gxQ, gxKV, gxKV, biasQ, nullptr, nullptr};
    dim3 g(1536 / BN, (M + BM - 1) / BM);
    mfma_gemm_kernel<<<g, 256, 0, st>>>(A, Bt, P, M, K, 1536, 512, 0);
}

static inline void mgemm256_qkv(hipStream_t st, const unsigned short* A, const unsigned short* Bt,
                                const float* biasQ,
                                const unsigned short* addQ, const int* gxQ,
                                const unsigned short* addKV, const int* gxKV,
                                unsigned short* Cq, unsigned short* Ck, unsigned short* Cv,
                                int M, int K)
{
    GemmDst P = {Cq, Ck, Cv, addQ, addKV, addKV,
                 gxQ, gxKV, gxKV, biasQ, nullptr, nullptr};
    dim3 g(1536 / TN, (M + TM - 1) / TM);
    mfma_gemm256_kernel<<<g, 512, 0, st>>>(A, Bt, P, M, K, 1536, 512, 0);
}

struct TcH { const float* W; unsigned short* Wt; int K, N; };
static inline void tcast_batch(hipStream_t st, const TcH* items, int cnt)
{
    TcB B{};
    int off = 0;
    for (int i = 0; i < cnt; ++i) {
        B.W[i] = items[i].W; B.Wt[i] = items[i].Wt;
        B.K[i] = items[i].K; B.N[i] = items[i].N;
        B.off[i] = off;
        off += (items[i].N >> 5) * (items[i].K >> 5);
    }
    B.off[cnt] = off; B.cnt = cnt;
    tcast_batch_kernel<<<off, 256, 0, st>>>(B);
}

static inline void zero(hipStream_t st, void* p, size_t nfloats)
{
    const int n4 = (int)(nfloats / 4);
    zero_kernel<<<(n4 + 255) / 256, 256, 0, st>>>((float4*)p, n4);
}

extern "C" void kernel_launch(void* const* d_in, const int* in_sizes, int n_in,
                              void* d_out, int out_size, void* d_ws, size_t ws_size,
                              hipStream_t stream)
{
    const float* x_in      = (const float*)d_in[0];
    const int*   edge_feat = (const int*)d_in[1];
    const int*   src_ids   = (const int*)d_in[2];
    const int*   dst_ids   = (const int*)d_in[3];
    const int*   lg_src    = (const int*)d_in[4];
    const int*   lg_dst    = (const int*)d_in[5];
    const float* rel_embed = (const float*)d_in[6];

    const float* n_Wq = (const float*)d_in[7];   const float* n_bq = (const float*)d_in[8];
    const float* n_Wk = (const float*)d_in[9];   const float* n_Wv = (const float*)d_in[10];
    const float* n_Wo = (const float*)d_in[11];  const float* n_bo = (const float*)d_in[12];
    const float* n_lg = (const float*)d_in[13];  const float* n_lb = (const float*)d_in[14];
    const float* n_f1 = (const float*)d_in[15];  const float* n_fb1 = (const float*)d_in[16];
    const float* n_f2 = (const float*)d_in[17];  const float* n_fb2 = (const float*)d_in[18];
    const float* n_fg = (const float*)d_in[19];  const float* n_fb = (const float*)d_in[20];

    const float* e_Wq = (const float*)d_in[21];  const float* e_bq = (const float*)d_in[22];
    const float* e_Wk = (const float*)d_in[23];  const float* e_Wv = (const float*)d_in[24];
    const float* e_Wo = (const float*)d_in[25];  const float* e_bo = (const float*)d_in[26];
    const float* e_lg = (const float*)d_in[27];  const float* e_lb = (const float*)d_in[28];
    const float* e_f1 = (const float*)d_in[29];  const float* e_fb1 = (const float*)d_in[30];
    const float* e_f2 = (const float*)d_in[31];  const float* e_fb2 = (const float*)d_in[32];
    const float* e_fg = (const float*)d_in[33];  const float* e_fb = (const float*)d_in[34];

    const int XSZ  = NNODES * DMODEL;
    const int LGSZ = NEDGES * DMODEL;

    // ---- workspace layout ---------------------------------------------------
    char* ws = (char*)d_ws;
    unsigned short* lg16  = (unsigned short*)(ws);               // 51,200,000 B
    unsigned short* ve16  = (unsigned short*)(ws + 51200000);    // 51,200,000 B
    int* n_off = (int*)(ws + 102400000);
    int* n_cur = (int*)(ws + 102420480);
    int* n_idx = (int*)(ws + 102440960);
    int* e_off = (int*)(ws + 102641664);
    int* e_cur = (int*)(ws + 102842368);
    int* e_idx = (int*)(ws + 103043072);                         // ends 103.84 MB
    unsigned short* xbufA = (unsigned short*)(ws + 110400000);   // 5,120,000 B
    unsigned short* xbufB = (unsigned short*)(ws + 115520000);   // 5,120,000 B

    // ---- d_out scratch (112.64 MB) -----------------------------------------
    char* ob = (char*)d_out;
    unsigned short* qe16 = (unsigned short*)(ob);                // 51.2 MB
    unsigned short* ke16 = (unsigned short*)(ob + 51200000);     // 51.2 MB
    unsigned short* ehid = (unsigned short*)(ob);                // 102.4 MB (edge FFN hidden)
    unsigned short* nq16 = (unsigned short*)(ob);
    unsigned short* nk16 = (unsigned short*)(ob + 5120000);
    unsigned short* nv16 = (unsigned short*)(ob + 10240000);
    unsigned short* nhid = (unsigned short*)(ob);                // 20.48 MB
    unsigned short* wtq  = (unsigned short*)(ob + 102400000);    // q|k|v contiguous
    unsigned short* wtk  = (unsigned short*)(ob + 102924288);
    unsigned short* wtv  = (unsigned short*)(ob + 103448576);
    unsigned short* wto  = (unsigned short*)(ob + 103972864);
    unsigned short* wtf1 = (unsigned short*)(ob + 104497152);    // 2 MB
    unsigned short* wtf2 = (unsigned short*)(ob + 106594304);    // 2 MB (ends 108.7 MB)

    float* out_f = (float*)d_out;

    // ---- init + CSR build ---------------------------------------------------
    cast_f2b_kernel<<<(XSZ + 255) / 256, 256, 0, stream>>>(x_in, xbufA, XSZ);
    gather_rel_kernel<<<(LGSZ + 255) / 256, 256, 0, stream>>>(rel_embed, edge_feat, lg16);

    zero(stream, n_cur, NNODES);
    zero(stream, e_cur, NEDGES);
    hist_kernel<<<(NEDGES + 255) / 256, 256, 0, stream>>>(dst_ids, n_cur, NEDGES);
    hist_kernel<<<(NELG + 255) / 256, 256, 0, stream>>>(lg_dst, e_cur, NELG);
    scan_kernel<<<1, 1024, 0, stream>>>(n_cur, n_off, n_cur, NNODES);
    scan_kernel<<<1, 1024, 0, stream>>>(e_cur, e_off, e_cur, NEDGES);
    scatter_kernel<<<(NEDGES + 255) / 256, 256, 0, stream>>>(dst_ids, n_cur, n_idx, NEDGES);
    scatter_kernel<<<(NELG + 255) / 256, 256, 0, stream>>>(lg_dst, e_cur, e_idx, NELG);

    unsigned short* xc = xbufA;
    unsigned short* xn = xbufB;

    for (int i = 0; i < NLAYERS; ++i) {
        const size_t wo  = (size_t)i * DMODEL * DMODEL;
        const size_t bo_ = (size_t)i * DMODEL;
        const size_t f1o = (size_t)i * DMODEL * 4 * DMODEL;
        const size_t b1o = (size_t)i * 4 * DMODEL;
        const size_t f2o = (size_t)i * 4 * DMODEL * DMODEL;
        const bool last = (i == NLAYERS - 1);

        // ================= node update (reads xc, lg16) =================
        {
            TcH items[6] = {
                {n_Wq + wo, wtq, 512, 512}, {n_Wk + wo, wtk, 512, 512},
                {n_Wv + wo, wtv, 512, 512}, {n_Wo + wo, wto, 512, 512},
                {n_f1 + f1o, wtf1, 512, 2048}, {n_f2 + f2o, wtf2, 2048, 512}};
            tcast_batch(stream, items, 6);
        }

        mgemm_qkv(stream, xc, wtq, n_bq + bo_,
                  nullptr, nullptr, nullptr, nullptr,
                  nq16, nk16, nv16, NNODES, 512);

        attend_kernel<<<(NNODES + 3) / 4, 256, 0, stream>>>(
            nq16, nk16, nv16, lg16, src_ids, n_off, n_idx, NNODES);

        mgemm(stream, nq16, wto, n_bo + bo_, xc, nullptr, xn, NNODES, 512, 512, 0);
        ln_kernel<<<(NNODES + 3) / 4, 256, 0, stream>>>(xn, n_lg + bo_, n_lb + bo_, NNODES, nullptr);
        mgemm(stream, xn, wtf1, n_fb1 + b1o, nullptr, nullptr, nhid, NNODES, 512, 2048, 1);
        mgemm(stream, nhid, wtf2, n_fb2 + bo_, xn, nullptr, xn, NNODES, 2048, 512, 0);
        ln_kernel<<<(NNODES + 3) / 4, 256, 0, stream>>>(xn, n_fg + bo_, n_fb + bo_, NNODES, nullptr);

        // ================= edge update (reads PRE-update xc) =================
        {
            TcH items[6] = {
                {e_Wq + wo, wtq, 512, 512}, {e_Wk + wo, wtk, 512, 512},
                {e_Wv + wo, wtv, 512, 512}, {e_Wo + wo, wto, 512, 512},
                {e_f1 + f1o, wtf1, 512, 2048}, {e_f2 + f2o, wtf2, 2048, 512}};
            tcast_batch(stream, items, 6);
        }

        mgemm256_qkv(stream, lg16, wtq, e_bq + bo_,
                     xc, dst_ids, xc, src_ids,
                     qe16, ke16, ve16, NEDGES, 512);

        attend_kernel<<<(NEDGES + 3) / 4, 256, 0, stream>>>(
            qe16, ke16, ve16, nullptr, lg_src, e_off, e_idx, NEDGES);

        mgemm(stream, qe16, wto, e_bo + bo_, lg16, nullptr, lg16, NEDGES, 512, 512, 0);
        ln_kernel<<<(NEDGES + 3) / 4, 256, 0, stream>>>(lg16, e_lg + bo_, e_lb + bo_, NEDGES, nullptr);

        // qe16/ke16 dead now -> 102.4 MB hidden buffer, 2 chunks of 25000
        for (int c = 0; c < 2; ++c) {
            unsigned short* y1c = lg16 + (size_t)c * 25000 * DMODEL;
            mgemm256(stream, y1c, wtf1, e_fb1 + b1o, nullptr, nullptr, ehid, 25000, 512, 2048, 1);
            mgemm(stream, ehid, wtf2, e_fb2 + bo_, y1c, nullptr, y1c, 25000, 2048, 512, 0);
        }
        // final layer: write edge output as fp32 directly into d_out
        // (ehid dead; node fp32 region [0,10.24MB) written at the very end)
        ln_kernel<<<(NEDGES + 3) / 4, 256, 0, stream>>>(
            lg16, e_fg + bo_, e_fb + bo_, NEDGES, last ? (out_f + XSZ) : nullptr);

        unsigned short* t = xc; xc = xn; xn = t;
    }

    // final: node bf16 -> fp32 d_out (edge half already written by fused LN)
    cast_b2f_kernel<<<(XSZ + 255) / 256, 256, 0, stream>>>(xc, out_f, XSZ);
}